// Round 4
// baseline (1822.018 us; speedup 1.0000x reference)
//
#include <hip/hip_runtime.h>
#include <hip/hip_bf16.h>
#include <math.h>

#define BB 8
#define NN 4096
#define DD 512
#define SLAB 2048                  // agents per slab
#define SROWS (BB * SLAB)          // 16384 rows per slab

typedef short bf16x8 __attribute__((ext_vector_type(8)));
typedef float f32x4 __attribute__((ext_vector_type(4)));

#define AS1 __attribute__((address_space(1)))
#define AS3 __attribute__((address_space(3)))

__device__ __forceinline__ void gload_lds16(const void* g, void* l) {
    __builtin_amdgcn_global_load_lds((const AS1 unsigned int*)g,
                                     (AS3 unsigned int*)l, 16, 0, 0);
}

__device__ __forceinline__ void split_bf16(float v, unsigned short& h, unsigned short& l) {
    __hip_bfloat16 bh = __float2bfloat16(v);         // RNE
    float hf = __bfloat162float(bh);
    __hip_bfloat16 bl = __float2bfloat16(v - hf);
    h = *reinterpret_cast<unsigned short*>(&bh);
    l = *reinterpret_cast<unsigned short*>(&bl);
}

// ---------------- generic contiguous split conv (used for net slabs)
__global__ __launch_bounds__(256)
void conv_split(const float* __restrict__ src, unsigned short* __restrict__ hi,
                unsigned short* __restrict__ lo)
{
    const size_t i = (size_t)blockIdx.x * 256 + threadIdx.x;   // float4 index
    float4 v = ((const float4*)src)[i];
    ushort4 h, l;
    split_bf16(v.x, h.x, l.x);
    split_bf16(v.y, h.y, l.y);
    split_bf16(v.z, h.z, l.z);
    split_bf16(v.w, h.w, l.w);
    ((ushort4*)hi)[i] = h;
    ((ushort4*)lo)[i] = l;
}

// ---------------- fused weight split: cand_w[c] + gate_w[c] x-part + inter-part
__global__ __launch_bounds__(256)
void conv_w3(const float* __restrict__ cw, const float* __restrict__ gw,
             unsigned short* __restrict__ cwh, unsigned short* __restrict__ cwl,
             unsigned short* __restrict__ gxh, unsigned short* __restrict__ gxl,
             unsigned short* __restrict__ gih, unsigned short* __restrict__ gil)
{
    const int blk = blockIdx.x;                 // 0..767
    const int i = (blk & 255) * 256 + threadIdx.x;   // 0..65535 float4 index
    const int n = i >> 7, kq = (i & 127) * 4;
    const float* src;
    unsigned short *oh, *ol;
    if (blk < 256)      { src = cw + (size_t)n * 512 + kq;        oh = cwh; ol = cwl; }
    else if (blk < 512) { src = gw + (size_t)n * 1024 + kq;       oh = gxh; ol = gxl; }
    else                { src = gw + (size_t)n * 1024 + 512 + kq; oh = gih; ol = gil; }
    float4 v = *(const float4*)src;
    ushort4 h, l;
    split_bf16(v.x, h.x, l.x);
    split_bf16(v.y, h.y, l.y);
    split_bf16(v.z, h.z, l.z);
    split_bf16(v.w, h.w, l.w);
    *(ushort4*)(oh + (size_t)n * 512 + kq) = h;
    *(ushort4*)(ol + (size_t)n * 512 + kq) = l;
}

// ---------------- x slab rows -> split planes [16384][512]
__global__ __launch_bounds__(256)
void conv_xs(const float* __restrict__ x, int nbase,
             unsigned short* __restrict__ hi, unsigned short* __restrict__ lo)
{
    const size_t i = (size_t)blockIdx.x * 256 + threadIdx.x;   // float4 idx, 2,097,152
    const int r = (int)(i >> 7), kq = (int)(i & 127) * 4;
    const int b = r >> 11, ii = r & (SLAB - 1);
    float4 v = *(const float4*)(x + ((size_t)(b << 12) + nbase + ii) * DD + kq);
    ushort4 h, l;
    split_bf16(v.x, h.x, l.x);
    split_bf16(v.y, h.y, l.y);
    split_bf16(v.z, h.z, l.z);
    split_bf16(v.w, h.w, l.w);
    *(ushort4*)(hi + (size_t)r * DD + kq) = h;
    *(ushort4*)(lo + (size_t)r * DD + kq) = l;
}

// ---------------- conversion + transpose: x fp32 [b][n][d] -> xT hi/lo bf16 [b][d][n]
__global__ __launch_bounds__(256)
void conv_xT(const float* __restrict__ x, unsigned short* __restrict__ th,
             unsigned short* __restrict__ tl)
{
    __shared__ unsigned short Th[64][65];
    __shared__ unsigned short Tl[64][65];
    const int n0 = blockIdx.x * 64, d0 = blockIdx.y * 64, b = blockIdx.z;
    const int t = threadIdx.x;
    const int r = t >> 4, c4 = (t & 15) * 4;
#pragma unroll
    for (int i = 0; i < 4; ++i) {
        int row = r + i * 16;
        float4 v = *(const float4*)(x + ((size_t)b * NN + n0 + row) * DD + d0 + c4);
        split_bf16(v.x, Th[row][c4 + 0], Tl[row][c4 + 0]);
        split_bf16(v.y, Th[row][c4 + 1], Tl[row][c4 + 1]);
        split_bf16(v.z, Th[row][c4 + 2], Tl[row][c4 + 2]);
        split_bf16(v.w, Th[row][c4 + 3], Tl[row][c4 + 3]);
    }
    __syncthreads();
    const int od = t >> 2;
    const int on0 = (t & 3) * 16;
    unsigned short hb[16], lb[16];
#pragma unroll
    for (int j = 0; j < 16; ++j) { hb[j] = Th[on0 + j][od]; lb[j] = Tl[on0 + j][od]; }
    const size_t obase = ((size_t)b * DD + d0 + od) * (size_t)NN + n0 + on0;
#pragma unroll
    for (int q = 0; q < 4; ++q) {
        ushort4 hv = {hb[q * 4 + 0], hb[q * 4 + 1], hb[q * 4 + 2], hb[q * 4 + 3]};
        ushort4 lv = {lb[q * 4 + 0], lb[q * 4 + 1], lb[q * 4 + 2], lb[q * 4 + 3]};
        *(ushort4*)(th + obase + q * 4) = hv;
        *(ushort4*)(tl + obase + q * 4) = lv;
    }
}

// ---------------- big GEMM v3: inter_slab = net_slab @ x  (split-3 bf16 MFMA)
// 8 waves (512 thr), 256x128 tile, ring-3 LDS (144 KB), counted vmcnt(6),
// ONE raw s_barrier per K-step, setprio around MFMA cluster.
// A planes: [2048][4096] (net slab, k contig). B planes: xT [b][512][4096].
// Output: inter slab split planes [b*2048 + m][512].
__global__ __launch_bounds__(512, 2)
void gemm_big(const unsigned short* __restrict__ Ah, const unsigned short* __restrict__ Al,
              const unsigned short* __restrict__ Bh, const unsigned short* __restrict__ Bl,
              unsigned short* __restrict__ Ch, unsigned short* __restrict__ Cl)
{
    // ring-3: per buffer A-plane [256][32] shorts (hi,lo), B-plane [128][32] (hi,lo)
    __shared__ alignas(16) unsigned short sA[3][2][256 * 32];   // 96 KB
    __shared__ alignas(16) unsigned short sB[3][2][128 * 32];   // 48 KB

    const int tid = threadIdx.x;
    const int lane = tid & 63;
    const int w = tid >> 6;                 // 0..7

    // grid (4,8,8) = 256 blocks; XCD-bijective chunking (256 % 8 == 0):
    // each XCD gets 32 consecutive tiles = all (n,b) for one m-tile -> A hot in L2.
    const int lin = blockIdx.x + (blockIdx.y << 2) + (blockIdx.z << 5);
    const int swz = (lin & 7) * 32 + (lin >> 3);
    const int n0 = (swz & 3) * 128;         // d tile (4)
    const int b  = (swz >> 2) & 7;          // batch (8)
    const int m0 = (swz >> 5) * 256;        // local agent tile (8)

    Bh += (size_t)b * DD * NN;
    Bl += (size_t)b * DD * NN;

    // staging: 16-row chunks. A: 16 chunks (waves take 2 each). B: 8 chunks (1 each).
    const int u2 = lane >> 2;                       // row in chunk 0..15
    const int sst = (u2 + (u2 >> 2)) & 3;
    const int kc = (lane & 3) ^ sst;                // pre-swizzled global k-slot
    const int cA0 = w * 2, cA1 = w * 2 + 1;
    const int cB = w;
    const size_t gA0 = (size_t)(m0 + cA0 * 16 + u2) * NN + kc * 8;
    const size_t gA1 = (size_t)(m0 + cA1 * 16 + u2) * NN + kc * 8;
    const size_t gB  = (size_t)(n0 + cB * 16 + u2) * NN + kc * 8;

    auto stage = [&](int r, int koff) {             // 6 wave-ops per wave
        gload_lds16(Ah + gA0 + koff, sA[r][0] + cA0 * 512);
        gload_lds16(Ah + gA1 + koff, sA[r][0] + cA1 * 512);
        gload_lds16(Al + gA0 + koff, sA[r][1] + cA0 * 512);
        gload_lds16(Al + gA1 + koff, sA[r][1] + cA1 * 512);
        gload_lds16(Bh + gB + koff,  sB[r][0] + cB * 512);
        gload_lds16(Bl + gB + koff,  sB[r][1] + cB * 512);
    };

    // fragment read offsets (swizzled read side, matches kc source swizzle)
    const int wm = (w & 3) * 64;            // 4 m-waves
    const int wn = (w >> 2) * 64;           // 2 n-waves
    const int fr = lane & 15;
    const int sf = (fr + (fr >> 2)) & 3;
    const int fslot = ((lane >> 4) ^ sf) * 16;      // byte offset of k-slot
    int offA[4], offB[4];
#pragma unroll
    for (int i = 0; i < 4; ++i) {
        offA[i] = (wm + i * 16 + fr) * 64 + fslot;
        offB[i] = (wn + i * 16 + fr) * 64 + fslot;
    }

    f32x4 acc[4][4] = {};

    // prologue: two tile-groups in flight (12 per-wave loads)
    stage(0, 0);
    stage(1, 32);

    for (int it = 0; it < NN / 32; ++it) {
        const int kt = it * 32;
        // wait for tile 'it' (oldest 6 of <=12 outstanding); tail drains fully
        if (kt + 32 < NN) asm volatile("s_waitcnt vmcnt(6)" ::: "memory");
        else              asm volatile("s_waitcnt vmcnt(0)" ::: "memory");
        __builtin_amdgcn_s_barrier();               // all waves: tile 'it' resident
        asm volatile("" ::: "memory");
        // issue prefetch for tile it+2 into ring slot (safe: its last readers
        // were iter it-1, separated by the barrier above)
        if (kt + 64 < NN) stage((it + 2) % 3, kt + 64);

        const unsigned short* pA = &sA[it % 3][0][0];
        const unsigned short* pAl = &sA[it % 3][1][0];
        const unsigned short* pB = &sB[it % 3][0][0];
        const unsigned short* pBl = &sB[it % 3][1][0];

        bf16x8 ah[4], al[4], bh[4], bl[4];
#pragma unroll
        for (int i = 0; i < 4; ++i) {
            ah[i] = *(const bf16x8*)((const char*)pA + offA[i]);
            al[i] = *(const bf16x8*)((const char*)pAl + offA[i]);
            bh[i] = *(const bf16x8*)((const char*)pB + offB[i]);
            bl[i] = *(const bf16x8*)((const char*)pBl + offB[i]);
        }
        __builtin_amdgcn_s_setprio(1);
#pragma unroll
        for (int mi = 0; mi < 4; ++mi)
#pragma unroll
            for (int ni = 0; ni < 4; ++ni) {
                acc[mi][ni] = __builtin_amdgcn_mfma_f32_16x16x32_bf16(al[mi], bh[ni], acc[mi][ni], 0, 0, 0);
                acc[mi][ni] = __builtin_amdgcn_mfma_f32_16x16x32_bf16(ah[mi], bl[ni], acc[mi][ni], 0, 0, 0);
                acc[mi][ni] = __builtin_amdgcn_mfma_f32_16x16x32_bf16(ah[mi], bh[ni], acc[mi][ni], 0, 0, 0);
            }
        __builtin_amdgcn_s_setprio(0);
    }

    // epilogue: write inter slab as split bf16 planes. row = b*2048 + local m.
    const int erow = (lane >> 4) * 4;
#pragma unroll
    for (int mi = 0; mi < 4; ++mi)
#pragma unroll
        for (int ni = 0; ni < 4; ++ni) {
            const int r0 = m0 + wm + mi * 16 + erow;
            const int col = n0 + wn + ni * 16 + fr;
#pragma unroll
            for (int r = 0; r < 4; ++r) {
                unsigned short h, l;
                split_bf16(acc[mi][ni][r], h, l);
                const size_t idx = ((size_t)b * SLAB + r0 + r) * DD + col;
                Ch[idx] = h;
                Cl[idx] = l;
            }
        }
}

// ---------------- small GEMM: C[r][n] = sum_k A[r][k] * B[n][k] (+bias) (+C)
// A planes [16384][512] k-contig; B planes [512][512] k-contig; C fp32 [16384][512].
__global__ __launch_bounds__(256, 2)
void gemm_small(const unsigned short* __restrict__ Ah, const unsigned short* __restrict__ Al,
                const unsigned short* __restrict__ Bh, const unsigned short* __restrict__ Bl,
                const float* __restrict__ bias, float* __restrict__ C, int accum)
{
    __shared__ alignas(16) unsigned short sAh[128 * 32];
    __shared__ alignas(16) unsigned short sAl[128 * 32];
    __shared__ alignas(16) unsigned short sBh[128 * 32];
    __shared__ alignas(16) unsigned short sBl[128 * 32];

    const int tid = threadIdx.x;
    const int lane = tid & 63;
    const int w = tid >> 6;

    // grid (4,128) = 512 blocks; bijective XCD chunking.
    const int lin = blockIdx.x + (blockIdx.y << 2);
    const int swz = (lin & 7) * 64 + (lin >> 3);
    const int n0 = (swz & 3) * 128;    // 4 n-tiles
    const int m0 = (swz >> 2) * 128;   // 128 m-tiles

    const int c0 = w * 2, c1 = c0 + 1;
    const int u2 = lane >> 2;
    const int sst = (u2 + (u2 >> 2)) & 3;
    const int kc = (lane & 3) ^ sst;
    const size_t gA0 = (size_t)(m0 + c0 * 16 + u2) * DD + kc * 8;
    const size_t gA1 = (size_t)(m0 + c1 * 16 + u2) * DD + kc * 8;
    const size_t gB0 = (size_t)(n0 + c0 * 16 + u2) * DD + kc * 8;
    const size_t gB1 = (size_t)(n0 + c1 * 16 + u2) * DD + kc * 8;
    unsigned short* lAh0 = sAh + c0 * 512; unsigned short* lAh1 = sAh + c1 * 512;
    unsigned short* lAl0 = sAl + c0 * 512; unsigned short* lAl1 = sAl + c1 * 512;
    unsigned short* lBh0 = sBh + c0 * 512; unsigned short* lBh1 = sBh + c1 * 512;
    unsigned short* lBl0 = sBl + c0 * 512; unsigned short* lBl1 = sBl + c1 * 512;

    const int wm = (w & 1) * 64, wn = (w >> 1) * 64;
    const int fr = lane & 15;
    const int sf = (fr + (fr >> 2)) & 3;
    const int fslot = ((lane >> 4) ^ sf) * 16;
    int offA[4], offB[4];
#pragma unroll
    for (int i = 0; i < 4; ++i) {
        offA[i] = (wm + i * 16 + fr) * 64 + fslot;
        offB[i] = (wn + i * 16 + fr) * 64 + fslot;
    }

    f32x4 acc[4][4] = {};

    for (int kt = 0; kt < DD; kt += 32) {
        __syncthreads();
        gload_lds16(Ah + gA0 + kt, lAh0);
        gload_lds16(Ah + gA1 + kt, lAh1);
        gload_lds16(Al + gA0 + kt, lAl0);
        gload_lds16(Al + gA1 + kt, lAl1);
        gload_lds16(Bh + gB0 + kt, lBh0);
        gload_lds16(Bh + gB1 + kt, lBh1);
        gload_lds16(Bl + gB0 + kt, lBl0);
        gload_lds16(Bl + gB1 + kt, lBl1);
        asm volatile("s_waitcnt vmcnt(0)" ::: "memory");
        __syncthreads();

        bf16x8 ah[4], al[4], bh[4], bl[4];
#pragma unroll
        for (int i = 0; i < 4; ++i) {
            ah[i] = *(const bf16x8*)((const char*)sAh + offA[i]);
            al[i] = *(const bf16x8*)((const char*)sAl + offA[i]);
            bh[i] = *(const bf16x8*)((const char*)sBh + offB[i]);
            bl[i] = *(const bf16x8*)((const char*)sBl + offB[i]);
        }
#pragma unroll
        for (int mi = 0; mi < 4; ++mi)
#pragma unroll
            for (int ni = 0; ni < 4; ++ni) {
                acc[mi][ni] = __builtin_amdgcn_mfma_f32_16x16x32_bf16(al[mi], bh[ni], acc[mi][ni], 0, 0, 0);
                acc[mi][ni] = __builtin_amdgcn_mfma_f32_16x16x32_bf16(ah[mi], bl[ni], acc[mi][ni], 0, 0, 0);
                acc[mi][ni] = __builtin_amdgcn_mfma_f32_16x16x32_bf16(ah[mi], bh[ni], acc[mi][ni], 0, 0, 0);
            }
    }

    const int erow = (lane >> 4) * 4;
#pragma unroll
    for (int mi = 0; mi < 4; ++mi)
#pragma unroll
        for (int ni = 0; ni < 4; ++ni) {
            const int r0 = m0 + wm + mi * 16 + erow;
            const int col = n0 + wn + ni * 16 + fr;
            const float bv = bias ? bias[col] : 0.0f;
#pragma unroll
            for (int r = 0; r < 4; ++r) {
                const size_t idx = (size_t)(r0 + r) * DD + col;
                float v = acc[mi][ni][r] + bv;
                if (accum) v += C[idx];
                C[idx] = v;
            }
        }
}

// ---------------- dual small GEMM: A=inter staged once, two B sets, two outputs.
//   candp[r][n] = sum_k inter[r][k] * cw[n][k] + cand_b[n]
//   gatep[r][n] += sum_k inter[r][k] * gwi[n][k]
__global__ __launch_bounds__(256, 2)
void gemm_small_dual(const unsigned short* __restrict__ Ah, const unsigned short* __restrict__ Al,
                     const unsigned short* __restrict__ Gh, const unsigned short* __restrict__ Gl,
                     const unsigned short* __restrict__ Wh, const unsigned short* __restrict__ Wl,
                     const float* __restrict__ cbias, float* __restrict__ gatep,
                     float* __restrict__ candp)
{
    __shared__ alignas(16) unsigned short sAh[128 * 32];
    __shared__ alignas(16) unsigned short sAl[128 * 32];
    __shared__ alignas(16) unsigned short sGh[128 * 32];
    __shared__ alignas(16) unsigned short sGl[128 * 32];
    __shared__ alignas(16) unsigned short sWh[128 * 32];
    __shared__ alignas(16) unsigned short sWl[128 * 32];

    const int tid = threadIdx.x;
    const int lane = tid & 63;
    const int w = tid >> 6;

    const int lin = blockIdx.x + (blockIdx.y << 2);
    const int swz = (lin & 7) * 64 + (lin >> 3);
    const int n0 = (swz & 3) * 128;
    const int m0 = (swz >> 2) * 128;

    const int c0 = w * 2, c1 = c0 + 1;
    const int u2 = lane >> 2;
    const int sst = (u2 + (u2 >> 2)) & 3;
    const int kc = (lane & 3) ^ sst;
    const size_t gA0 = (size_t)(m0 + c0 * 16 + u2) * DD + kc * 8;
    const size_t gA1 = (size_t)(m0 + c1 * 16 + u2) * DD + kc * 8;
    const size_t gB0 = (size_t)(n0 + c0 * 16 + u2) * DD + kc * 8;
    const size_t gB1 = (size_t)(n0 + c1 * 16 + u2) * DD + kc * 8;

    const int wm = (w & 1) * 64, wn = (w >> 1) * 64;
    const int fr = lane & 15;
    const int sf = (fr + (fr >> 2)) & 3;
    const int fslot = ((lane >> 4) ^ sf) * 16;
    int offA[4], offB[4];
#pragma unroll
    for (int i = 0; i < 4; ++i) {
        offA[i] = (wm + i * 16 + fr) * 64 + fslot;
        offB[i] = (wn + i * 16 + fr) * 64 + fslot;
    }

    f32x4 accG[4][4] = {};
    f32x4 accC[4][4] = {};

    for (int kt = 0; kt < DD; kt += 32) {
        __syncthreads();
        gload_lds16(Ah + gA0 + kt, sAh + c0 * 512);
        gload_lds16(Ah + gA1 + kt, sAh + c1 * 512);
        gload_lds16(Al + gA0 + kt, sAl + c0 * 512);
        gload_lds16(Al + gA1 + kt, sAl + c1 * 512);
        gload_lds16(Gh + gB0 + kt, sGh + c0 * 512);
        gload_lds16(Gh + gB1 + kt, sGh + c1 * 512);
        gload_lds16(Gl + gB0 + kt, sGl + c0 * 512);
        gload_lds16(Gl + gB1 + kt, sGl + c1 * 512);
        gload_lds16(Wh + gB0 + kt, sWh + c0 * 512);
        gload_lds16(Wh + gB1 + kt, sWh + c1 * 512);
        gload_lds16(Wl + gB0 + kt, sWl + c0 * 512);
        gload_lds16(Wl + gB1 + kt, sWl + c1 * 512);
        asm volatile("s_waitcnt vmcnt(0)" ::: "memory");
        __syncthreads();

        bf16x8 ah[4], al[4], bh[4], bl[4];
#pragma unroll
        for (int i = 0; i < 4; ++i) {
            ah[i] = *(const bf16x8*)((const char*)sAh + offA[i]);
            al[i] = *(const bf16x8*)((const char*)sAl + offA[i]);
        }
        // set 1: gate-inter weights
#pragma unroll
        for (int i = 0; i < 4; ++i) {
            bh[i] = *(const bf16x8*)((const char*)sGh + offB[i]);
            bl[i] = *(const bf16x8*)((const char*)sGl + offB[i]);
        }
#pragma unroll
        for (int mi = 0; mi < 4; ++mi)
#pragma unroll
            for (int ni = 0; ni < 4; ++ni) {
                accG[mi][ni] = __builtin_amdgcn_mfma_f32_16x16x32_bf16(al[mi], bh[ni], accG[mi][ni], 0, 0, 0);
                accG[mi][ni] = __builtin_amdgcn_mfma_f32_16x16x32_bf16(ah[mi], bl[ni], accG[mi][ni], 0, 0, 0);
                accG[mi][ni] = __builtin_amdgcn_mfma_f32_16x16x32_bf16(ah[mi], bh[ni], accG[mi][ni], 0, 0, 0);
            }
        // set 2: cand weights (reuse b-frag registers)
#pragma unroll
        for (int i = 0; i < 4; ++i) {
            bh[i] = *(const bf16x8*)((const char*)sWh + offB[i]);
            bl[i] = *(const bf16x8*)((const char*)sWl + offB[i]);
        }
#pragma unroll
        for (int mi = 0; mi < 4; ++mi)
#pragma unroll
            for (int ni = 0; ni < 4; ++ni) {
                accC[mi][ni] = __builtin_amdgcn_mfma_f32_16x16x32_bf16(al[mi], bh[ni], accC[mi][ni], 0, 0, 0);
                accC[mi][ni] = __builtin_amdgcn_mfma_f32_16x16x32_bf16(ah[mi], bl[ni], accC[mi][ni], 0, 0, 0);
                accC[mi][ni] = __builtin_amdgcn_mfma_f32_16x16x32_bf16(ah[mi], bh[ni], accC[mi][ni], 0, 0, 0);
            }
    }

    const int erow = (lane >> 4) * 4;
#pragma unroll
    for (int mi = 0; mi < 4; ++mi)
#pragma unroll
        for (int ni = 0; ni < 4; ++ni) {
            const int r0 = m0 + wm + mi * 16 + erow;
            const int col = n0 + wn + ni * 16 + fr;
            const float cb = cbias[col];
#pragma unroll
            for (int r = 0; r < 4; ++r) {
                const size_t idx = (size_t)(r0 + r) * DD + col;
                gatep[idx] += accG[mi][ni][r];
                candp[idx] = accC[mi][ni][r] + cb;
            }
        }
}

// ---------------- fused pointwise + LN + weighted accumulate (+energy at c==1)
__global__ __launch_bounds__(128)
void pw_slab(const float* __restrict__ x, const float* __restrict__ gp_,
             const float* __restrict__ cp_, const float* __restrict__ lg,
             const float* __restrict__ lb, const float* __restrict__ cmix,
             int c, int nbase, float* __restrict__ out, float* __restrict__ energy)
{
    __shared__ float sm[4];
    const int rloc = blockIdx.x;                       // 0..16383
    const int b = rloc >> 11, ii = rloc & (SLAB - 1);
    const int grow = (b << 12) + nbase + ii;           // global row
    const int tid = threadIdx.x;
    const size_t lbase = (size_t)rloc * DD + tid * 4;
    const size_t gbase = (size_t)grow * DD + tid * 4;

    float4 g4 = *(const float4*)(gp_ + lbase);
    float4 c4 = *(const float4*)(cp_ + lbase);
    float4 x4 = *(const float4*)(x + gbase);
    float gv[4] = {g4.x, g4.y, g4.z, g4.w};
    float cv[4] = {c4.x, c4.y, c4.z, c4.w};
    float xv[4] = {x4.x, x4.y, x4.z, x4.w};
    float h[4];
#pragma unroll
    for (int j = 0; j < 4; ++j) {
        float gate = 1.0f / (1.0f + expf(-gv[j]));
        float cand = 0.5f * cv[j] * (1.0f + erff(cv[j] * 0.70710678118654752440f));
        h[j] = gate * cand + (1.0f - gate) * xv[j];
    }

    const int lane = tid & 63, wid = tid >> 6;
    float s = h[0] + h[1] + h[2] + h[3];
#pragma unroll
    for (int off = 32; off > 0; off >>= 1) s += __shfl_xor(s, off, 64);
    if (lane == 0) sm[wid] = s;
    __syncthreads();
    float mu = (sm[0] + sm[1]) * (1.0f / 512.0f);
    float vs = 0.0f;
#pragma unroll
    for (int j = 0; j < 4; ++j) { float d = h[j] - mu; vs += d * d; }
#pragma unroll
    for (int off = 32; off > 0; off >>= 1) vs += __shfl_xor(vs, off, 64);
    if (lane == 0) sm[2 + wid] = vs;
    __syncthreads();
    float var = (sm[2] + sm[3]) * (1.0f / 512.0f);
    float rstd = 1.0f / sqrtf(var + 1e-5f);

    float m0 = cmix[0], m1 = cmix[1];
    float mx = fmaxf(m0, m1);
    float e0 = expf(m0 - mx), e1 = expf(m1 - mx);
    float wgt = ((c == 0) ? e0 : e1) / (e0 + e1);

    const int dix = tid * 4;
    float4 lg4 = *(const float4*)(lg + dix);
    float4 lb4 = *(const float4*)(lb + dix);
    float lgv[4] = {lg4.x, lg4.y, lg4.z, lg4.w};
    float lbv[4] = {lb4.x, lb4.y, lb4.z, lb4.w};
    float ov[4];
    if (c == 0) {
#pragma unroll
        for (int j = 0; j < 4; ++j)
            ov[j] = wgt * ((h[j] - mu) * rstd * lgv[j] + lbv[j]);
    } else {
        float4 o4 = *(const float4*)(out + gbase);
        ov[0] = o4.x; ov[1] = o4.y; ov[2] = o4.z; ov[3] = o4.w;
#pragma unroll
        for (int j = 0; j < 4; ++j)
            ov[j] += wgt * ((h[j] - mu) * rstd * lgv[j] + lbv[j]);
    }
    float4 st = {ov[0], ov[1], ov[2], ov[3]};
    *(float4*)(out + gbase) = st;

    if (c == 1) {
        // energy = ||out row||
        float s2 = ov[0] * ov[0] + ov[1] * ov[1] + ov[2] * ov[2] + ov[3] * ov[3];
#pragma unroll
        for (int off = 32; off > 0; off >>= 1) s2 += __shfl_xor(s2, off, 64);
        __syncthreads();
        if (lane == 0) sm[wid] = s2;
        __syncthreads();
        if (tid == 0) energy[grow] = sqrtf(sm[0] + sm[1]);
    }
}

// ---------------- per-batch top-k radix select; writes mask IN-PLACE over energy
__global__ __launch_bounds__(1024)
void topk_kernel(float* __restrict__ energy, const int* __restrict__ kptr)
{
    __shared__ unsigned keys[NN];
    __shared__ int hist[256];
    __shared__ int wsum[16];
    __shared__ unsigned sh_pfx;
    __shared__ int sh_need;

    const int b = blockIdx.x, tid = threadIdx.x;
    float* e = energy + (size_t)b * NN;
    for (int n = tid; n < NN; n += 1024) keys[n] = __float_as_uint(e[n]);
    const int K = *kptr;
    if (tid == 0) { sh_pfx = 0u; sh_need = K; }
    __syncthreads();

    for (int round = 0; round < 4; ++round) {
        const int shift = 24 - 8 * round;
        if (tid < 256) hist[tid] = 0;
        __syncthreads();
        const unsigned pfx = sh_pfx;
        const unsigned mhi = (round == 0) ? 0u : (0xFFFFFFFFu << (shift + 8));
        for (int n = tid; n < NN; n += 1024) {
            unsigned kv = keys[n];
            if ((kv & mhi) == pfx) atomicAdd(&hist[(kv >> shift) & 255], 1);
        }
        __syncthreads();
        if (tid == 0) {
            int need = sh_need;
            int d = 255;
            for (;; --d) {
                int cct = hist[d];
                if (need <= cct) break;
                need -= cct;
            }
            sh_pfx = pfx | ((unsigned)d << shift);
            sh_need = need;
        }
        __syncthreads();
    }

    const unsigned T = sh_pfx;
    const int need = sh_need;

    const int n0 = tid * 4;
    unsigned kv[4]; int eq[4]; int loc[4];
    int s = 0;
#pragma unroll
    for (int j = 0; j < 4; ++j) {
        kv[j] = keys[n0 + j];
        eq[j] = (kv[j] == T) ? 1 : 0;
        loc[j] = s; s += eq[j];
    }
    const int lane = tid & 63, wid = tid >> 6;
    int v = s;
#pragma unroll
    for (int off = 1; off < 64; off <<= 1) {
        int u = __shfl_up(v, off, 64);
        if (lane >= off) v += u;
    }
    if (lane == 63) wsum[wid] = v;
    __syncthreads();
    if (tid == 0) {
        int acc = 0;
        for (int w2 = 0; w2 < 16; ++w2) { int t = wsum[w2]; wsum[w2] = acc; acc += t; }
    }
    __syncthreads();
    const int base = wsum[wid] + (v - s);
    const float scale = (float)(4096.0 / (double)K);
#pragma unroll
    for (int j = 0; j < 4; ++j) {
        bool sel = (kv[j] > T) || (eq[j] && (base + loc[j]) < need);
        e[n0 + j] = sel ? scale : 0.0f;
    }
}

__global__ __launch_bounds__(128)
void mask_kernel(float* __restrict__ out, const float* __restrict__ mscale)
{
    const int row = blockIdx.x;
    const int tid = threadIdx.x;
    const size_t base = (size_t)row * DD + tid * 4;
    const float sc = mscale[row];
    float4 v = *(const float4*)(out + base);
    v.x *= sc; v.y *= sc; v.z *= sc; v.w *= sc;
    *(float4*)(out + base) = v;
}

extern "C" void kernel_launch(void* const* d_in, const int* in_sizes, int n_in,
                              void* d_out, int out_size, void* d_ws, size_t ws_size,
                              hipStream_t stream)
{
    const float* x      = (const float*)d_in[0];
    const float* net    = (const float*)d_in[1];
    const float* gate_w = (const float*)d_in[2];
    const float* gate_b = (const float*)d_in[3];
    const float* cand_w = (const float*)d_in[4];
    const float* cand_b = (const float*)d_in[5];
    const float* ln_g   = (const float*)d_in[6];
    const float* ln_b   = (const float*)d_in[7];
    const float* cmix   = (const float*)d_in[8];
    const int*   kptr   = (const int*)d_in[9];
    float* out = (float*)d_out;

    const size_t ROWS  = (size_t)BB * NN;      // 32768
    const size_t PLANE = ROWS * DD;            // 16,777,216 elems

    // Workspace carve — total 201,457,664 B (<= proven 201,588,736):
    //   Slot A: xT hi/lo bf16 [b][d][n]                 67,108,864
    //   Slot N: net slab split (2048x4096 hi+lo)        33,554,432
    //           (reused for weight splits after gemm_big frees it)
    //   Slot I: inter slab split [16384][512] hi+lo     33,554,432
    //   Slot X: x slab split hi+lo -> candp fp32        33,554,432
    //   Slot G: gatep fp32 [16384][512]                 33,554,432
    //   energy [32768] fp32 (topk writes mask in-place)    131,072
    char* p = (char*)d_ws;
    unsigned short* xTh = (unsigned short*)p;             p += PLANE * 2;
    unsigned short* xTl = (unsigned short*)p;             p += PLANE * 2;
    char* slotN = p;                                      p += (size_t)SLAB * NN * 2 * 2;
    unsigned short* netsh = (unsigned short*)slotN;
    unsigned short* netsl = netsh + (size_t)SLAB * NN;
    unsigned short* cwh = (unsigned short*)slotN;          // weight aliases (post-gemm_big)
    unsigned short* cwl = cwh + 512 * 512;
    unsigned short* gxh = cwl + 512 * 512;
    unsigned short* gxl = gxh + 512 * 512;
    unsigned short* gih = gxl + 512 * 512;
    unsigned short* gil = gih + 512 * 512;
    unsigned short* inth = (unsigned short*)p;            p += (size_t)SROWS * DD * 2;
    unsigned short* intl = (unsigned short*)p;            p += (size_t)SROWS * DD * 2;
    char* slotX = p;                                      p += (size_t)SROWS * DD * 4;
    unsigned short* xsh = (unsigned short*)slotX;
    unsigned short* xsl = xsh + (size_t)SROWS * DD;
    float* candp = (float*)slotX;                         // alias (post-gate0)
    float* gatep = (float*)p;                             p += (size_t)SROWS * DD * 4;
    float* energy = (float*)p;

    // x -> transposed split planes (once)
    conv_xT<<<dim3(NN / 64, DD / 64, BB), 256, 0, stream>>>(x, xTh, xTl);

    for (int c = 0; c < 2; ++c) {
        for (int s = 0; s < 2; ++s) {
            const int nbase = s * SLAB;
            // net slab -> split planes
            conv_split<<<(SLAB * NN / 4) / 256, 256, 0, stream>>>(
                net + (size_t)c * NN * NN + (size_t)nbase * NN, netsh, netsl);
            // inter slab = net_slab @ x   (split-3 MFMA, 8-wave ring-3 pipeline)
            gemm_big<<<dim3(4, 8, 8), 512, 0, stream>>>(
                netsh, netsl, xTh, xTl, inth, intl);
            // weights -> split planes (into slot N, now free)
            conv_w3<<<768, 256, 0, stream>>>(
                cand_w + (size_t)c * DD * DD, gate_w + (size_t)c * DD * 2 * DD,
                cwh, cwl, gxh, gxl, gih, gil);
            // x slab -> split planes
            conv_xs<<<(SROWS * DD / 4) / 256, 256, 0, stream>>>(x, nbase, xsh, xsl);
            // gate_pre = x @ gwx^T + gate_b   (reads xs; must precede candp overwrite)
            gemm_small<<<dim3(4, SROWS / 128), 256, 0, stream>>>(
                xsh, xsl, gxh, gxl, gate_b + (size_t)c * DD, gatep, 0);
            // fused: cand_pre = inter @ cw^T + cand_b (overwrites xs slot)
            //        gate_pre += inter @ gwi^T
            gemm_small_dual<<<dim3(4, SROWS / 128), 256, 0, stream>>>(
                inth, intl, gih, gil, cwh, cwl, cand_b + (size_t)c * DD, gatep, candp);
            // pointwise + LN + accumulate (+energy at c==1)
            pw_slab<<<SROWS, 128, 0, stream>>>(
                x, gatep, candp, ln_g + (size_t)c * DD, ln_b + (size_t)c * DD,
                cmix, c, nbase, out, energy);
        }
    }

    topk_kernel<<<BB, 1024, 0, stream>>>(energy, kptr);
    mask_kernel<<<(int)ROWS, 128, 0, stream>>>(out, energy);
}

// Round 6
// 1675.357 us; speedup vs baseline: 1.0875x; 1.0875x over previous
//
#include <hip/hip_runtime.h>
#include <hip/hip_bf16.h>
#include <math.h>

#define BB 8
#define NN 4096
#define DD 512
#define SLAB 2048                  // agents per slab
#define SROWS (BB * SLAB)          // 16384 rows per slab

typedef short bf16x8 __attribute__((ext_vector_type(8)));
typedef float f32x4 __attribute__((ext_vector_type(4)));

#define AS1 __attribute__((address_space(1)))
#define AS3 __attribute__((address_space(3)))

__device__ __forceinline__ void gload_lds16(const void* g, void* l) {
    __builtin_amdgcn_global_load_lds((const AS1 unsigned int*)g,
                                     (AS3 unsigned int*)l, 16, 0, 0);
}

__device__ __forceinline__ void split_bf16(float v, unsigned short& h, unsigned short& l) {
    __hip_bfloat16 bh = __float2bfloat16(v);         // RNE
    float hf = __bfloat162float(bh);
    __hip_bfloat16 bl = __float2bfloat16(v - hf);
    h = *reinterpret_cast<unsigned short*>(&bh);
    l = *reinterpret_cast<unsigned short*>(&bl);
}

// ---------------- generic contiguous split conv (used for net slabs)
__global__ __launch_bounds__(256)
void conv_split(const float* __restrict__ src, unsigned short* __restrict__ hi,
                unsigned short* __restrict__ lo)
{
    const size_t i = (size_t)blockIdx.x * 256 + threadIdx.x;   // float4 index
    float4 v = ((const float4*)src)[i];
    ushort4 h, l;
    split_bf16(v.x, h.x, l.x);
    split_bf16(v.y, h.y, l.y);
    split_bf16(v.z, h.z, l.z);
    split_bf16(v.w, h.w, l.w);
    ((ushort4*)hi)[i] = h;
    ((ushort4*)lo)[i] = l;
}

// ---------------- fused weight split: cand_w[c] + gate_w[c] x-part + inter-part
__global__ __launch_bounds__(256)
void conv_w3(const float* __restrict__ cw, const float* __restrict__ gw,
             unsigned short* __restrict__ cwh, unsigned short* __restrict__ cwl,
             unsigned short* __restrict__ gxh, unsigned short* __restrict__ gxl,
             unsigned short* __restrict__ gih, unsigned short* __restrict__ gil)
{
    const int blk = blockIdx.x;                 // 0..767
    const int i = (blk & 255) * 256 + threadIdx.x;   // 0..65535 float4 index
    const int n = i >> 7, kq = (i & 127) * 4;
    const float* src;
    unsigned short *oh, *ol;
    if (blk < 256)      { src = cw + (size_t)n * 512 + kq;        oh = cwh; ol = cwl; }
    else if (blk < 512) { src = gw + (size_t)n * 1024 + kq;       oh = gxh; ol = gxl; }
    else                { src = gw + (size_t)n * 1024 + 512 + kq; oh = gih; ol = gil; }
    float4 v = *(const float4*)src;
    ushort4 h, l;
    split_bf16(v.x, h.x, l.x);
    split_bf16(v.y, h.y, l.y);
    split_bf16(v.z, h.z, l.z);
    split_bf16(v.w, h.w, l.w);
    *(ushort4*)(oh + (size_t)n * 512 + kq) = h;
    *(ushort4*)(ol + (size_t)n * 512 + kq) = l;
}

// ---------------- x slab rows -> split planes [16384][512]
__global__ __launch_bounds__(256)
void conv_xs(const float* __restrict__ x, int nbase,
             unsigned short* __restrict__ hi, unsigned short* __restrict__ lo)
{
    const size_t i = (size_t)blockIdx.x * 256 + threadIdx.x;   // float4 idx, 2,097,152
    const int r = (int)(i >> 7), kq = (int)(i & 127) * 4;
    const int b = r >> 11, ii = r & (SLAB - 1);
    float4 v = *(const float4*)(x + ((size_t)(b << 12) + nbase + ii) * DD + kq);
    ushort4 h, l;
    split_bf16(v.x, h.x, l.x);
    split_bf16(v.y, h.y, l.y);
    split_bf16(v.z, h.z, l.z);
    split_bf16(v.w, h.w, l.w);
    *(ushort4*)(hi + (size_t)r * DD + kq) = h;
    *(ushort4*)(lo + (size_t)r * DD + kq) = l;
}

// ---------------- conversion + transpose: x fp32 [b][n][d] -> xT hi/lo bf16 [b][d][n]
__global__ __launch_bounds__(256)
void conv_xT(const float* __restrict__ x, unsigned short* __restrict__ th,
             unsigned short* __restrict__ tl)
{
    __shared__ unsigned short Th[64][65];
    __shared__ unsigned short Tl[64][65];
    const int n0 = blockIdx.x * 64, d0 = blockIdx.y * 64, b = blockIdx.z;
    const int t = threadIdx.x;
    const int r = t >> 4, c4 = (t & 15) * 4;
#pragma unroll
    for (int i = 0; i < 4; ++i) {
        int row = r + i * 16;
        float4 v = *(const float4*)(x + ((size_t)b * NN + n0 + row) * DD + d0 + c4);
        split_bf16(v.x, Th[row][c4 + 0], Tl[row][c4 + 0]);
        split_bf16(v.y, Th[row][c4 + 1], Tl[row][c4 + 1]);
        split_bf16(v.z, Th[row][c4 + 2], Tl[row][c4 + 2]);
        split_bf16(v.w, Th[row][c4 + 3], Tl[row][c4 + 3]);
    }
    __syncthreads();
    const int od = t >> 2;
    const int on0 = (t & 3) * 16;
    unsigned short hb[16], lb[16];
#pragma unroll
    for (int j = 0; j < 16; ++j) { hb[j] = Th[on0 + j][od]; lb[j] = Tl[on0 + j][od]; }
    const size_t obase = ((size_t)b * DD + d0 + od) * (size_t)NN + n0 + on0;
#pragma unroll
    for (int q = 0; q < 4; ++q) {
        ushort4 hv = {hb[q * 4 + 0], hb[q * 4 + 1], hb[q * 4 + 2], hb[q * 4 + 3]};
        ushort4 lv = {lb[q * 4 + 0], lb[q * 4 + 1], lb[q * 4 + 2], lb[q * 4 + 3]};
        *(ushort4*)(th + obase + q * 4) = hv;
        *(ushort4*)(tl + obase + q * 4) = lv;
    }
}

// ---------------- big GEMM (R3-proven): inter_slab = net_slab @ x  (split-3 bf16)
// A planes: [2048][4096] (net slab, k contig). B planes: xT [b][512][4096] (k contig).
// Output: inter slab split planes [b*2048 + m][512].
__global__ __launch_bounds__(256, 2)
void gemm_big(const unsigned short* __restrict__ Ah, const unsigned short* __restrict__ Al,
              const unsigned short* __restrict__ Bh, const unsigned short* __restrict__ Bl,
              unsigned short* __restrict__ Ch, unsigned short* __restrict__ Cl)
{
    __shared__ alignas(16) unsigned short sAh[128 * 32];
    __shared__ alignas(16) unsigned short sAl[128 * 32];
    __shared__ alignas(16) unsigned short sBh[128 * 32];
    __shared__ alignas(16) unsigned short sBl[128 * 32];

    const int tid = threadIdx.x;
    const int lane = tid & 63;
    const int w = tid >> 6;

    // grid (4,8,16) = 512 blocks; XCD-bijective chunking.
    const int lin = blockIdx.x + (blockIdx.y << 2) + (blockIdx.z << 5);
    const int swz = (lin & 7) * 64 + (lin >> 3);
    const int n0 = (swz & 3) * 128;        // d tile (4)
    const int b  = (swz >> 2) & 7;         // batch (8)
    const int m0 = (swz >> 5) * 128;       // local agent tile (16)

    Bh += (size_t)b * DD * NN;
    Bl += (size_t)b * DD * NN;

    const int c0 = w * 2, c1 = c0 + 1;
    const int u2 = lane >> 2;
    const int sst = (u2 + (u2 >> 2)) & 3;
    const int kc = (lane & 3) ^ sst;
    const size_t gA0 = (size_t)(m0 + c0 * 16 + u2) * NN + kc * 8;
    const size_t gA1 = (size_t)(m0 + c1 * 16 + u2) * NN + kc * 8;
    const size_t gB0 = (size_t)(n0 + c0 * 16 + u2) * NN + kc * 8;
    const size_t gB1 = (size_t)(n0 + c1 * 16 + u2) * NN + kc * 8;
    unsigned short* lAh0 = sAh + c0 * 512; unsigned short* lAh1 = sAh + c1 * 512;
    unsigned short* lAl0 = sAl + c0 * 512; unsigned short* lAl1 = sAl + c1 * 512;
    unsigned short* lBh0 = sBh + c0 * 512; unsigned short* lBh1 = sBh + c1 * 512;
    unsigned short* lBl0 = sBl + c0 * 512; unsigned short* lBl1 = sBl + c1 * 512;

    const int wm = (w & 1) * 64, wn = (w >> 1) * 64;
    const int fr = lane & 15;
    const int sf = (fr + (fr >> 2)) & 3;
    const int fslot = ((lane >> 4) ^ sf) * 16;
    int offA[4], offB[4];
#pragma unroll
    for (int i = 0; i < 4; ++i) {
        offA[i] = (wm + i * 16 + fr) * 64 + fslot;
        offB[i] = (wn + i * 16 + fr) * 64 + fslot;
    }

    f32x4 acc[4][4] = {};

    for (int kt = 0; kt < NN; kt += 32) {
        __syncthreads();
        gload_lds16(Ah + gA0 + kt, lAh0);
        gload_lds16(Ah + gA1 + kt, lAh1);
        gload_lds16(Al + gA0 + kt, lAl0);
        gload_lds16(Al + gA1 + kt, lAl1);
        gload_lds16(Bh + gB0 + kt, lBh0);
        gload_lds16(Bh + gB1 + kt, lBh1);
        gload_lds16(Bl + gB0 + kt, lBl0);
        gload_lds16(Bl + gB1 + kt, lBl1);
        asm volatile("s_waitcnt vmcnt(0)" ::: "memory");
        __syncthreads();

        bf16x8 ah[4], al[4], bh[4], bl[4];
#pragma unroll
        for (int i = 0; i < 4; ++i) {
            ah[i] = *(const bf16x8*)((const char*)sAh + offA[i]);
            al[i] = *(const bf16x8*)((const char*)sAl + offA[i]);
            bh[i] = *(const bf16x8*)((const char*)sBh + offB[i]);
            bl[i] = *(const bf16x8*)((const char*)sBl + offB[i]);
        }
#pragma unroll
        for (int mi = 0; mi < 4; ++mi)
#pragma unroll
            for (int ni = 0; ni < 4; ++ni) {
                acc[mi][ni] = __builtin_amdgcn_mfma_f32_16x16x32_bf16(al[mi], bh[ni], acc[mi][ni], 0, 0, 0);
                acc[mi][ni] = __builtin_amdgcn_mfma_f32_16x16x32_bf16(ah[mi], bl[ni], acc[mi][ni], 0, 0, 0);
                acc[mi][ni] = __builtin_amdgcn_mfma_f32_16x16x32_bf16(ah[mi], bh[ni], acc[mi][ni], 0, 0, 0);
            }
    }

    // epilogue: write inter slab as split bf16 planes. row = b*2048 + local m.
    const int erow = (lane >> 4) * 4;
#pragma unroll
    for (int mi = 0; mi < 4; ++mi)
#pragma unroll
        for (int ni = 0; ni < 4; ++ni) {
            const int r0 = m0 + wm + mi * 16 + erow;
            const int col = n0 + wn + ni * 16 + fr;
#pragma unroll
            for (int r = 0; r < 4; ++r) {
                unsigned short h, l;
                split_bf16(acc[mi][ni][r], h, l);
                const size_t idx = ((size_t)b * SLAB + r0 + r) * DD + col;
                Ch[idx] = h;
                Cl[idx] = l;
            }
        }
}

// ---------------- small GEMM: C[r][n] = sum_k A[r][k] * B[n][k] (+bias)
// A planes [16384][512] k-contig; B planes [512][512] k-contig; C fp32 [16384][512].
__global__ __launch_bounds__(256, 2)
void gemm_small(const unsigned short* __restrict__ Ah, const unsigned short* __restrict__ Al,
                const unsigned short* __restrict__ Bh, const unsigned short* __restrict__ Bl,
                const float* __restrict__ bias, float* __restrict__ C)
{
    __shared__ alignas(16) unsigned short sAh[128 * 32];
    __shared__ alignas(16) unsigned short sAl[128 * 32];
    __shared__ alignas(16) unsigned short sBh[128 * 32];
    __shared__ alignas(16) unsigned short sBl[128 * 32];

    const int tid = threadIdx.x;
    const int lane = tid & 63;
    const int w = tid >> 6;

    const int lin = blockIdx.x + (blockIdx.y << 2);
    const int swz = (lin & 7) * 64 + (lin >> 3);
    const int n0 = (swz & 3) * 128;    // 4 n-tiles
    const int m0 = (swz >> 2) * 128;   // 128 m-tiles

    const int c0 = w * 2, c1 = c0 + 1;
    const int u2 = lane >> 2;
    const int sst = (u2 + (u2 >> 2)) & 3;
    const int kc = (lane & 3) ^ sst;
    const size_t gA0 = (size_t)(m0 + c0 * 16 + u2) * DD + kc * 8;
    const size_t gA1 = (size_t)(m0 + c1 * 16 + u2) * DD + kc * 8;
    const size_t gB0 = (size_t)(n0 + c0 * 16 + u2) * DD + kc * 8;
    const size_t gB1 = (size_t)(n0 + c1 * 16 + u2) * DD + kc * 8;
    unsigned short* lAh0 = sAh + c0 * 512; unsigned short* lAh1 = sAh + c1 * 512;
    unsigned short* lAl0 = sAl + c0 * 512; unsigned short* lAl1 = sAl + c1 * 512;
    unsigned short* lBh0 = sBh + c0 * 512; unsigned short* lBh1 = sBh + c1 * 512;
    unsigned short* lBl0 = sBl + c0 * 512; unsigned short* lBl1 = sBl + c1 * 512;

    const int wm = (w & 1) * 64, wn = (w >> 1) * 64;
    const int fr = lane & 15;
    const int sf = (fr + (fr >> 2)) & 3;
    const int fslot = ((lane >> 4) ^ sf) * 16;
    int offA[4], offB[4];
#pragma unroll
    for (int i = 0; i < 4; ++i) {
        offA[i] = (wm + i * 16 + fr) * 64 + fslot;
        offB[i] = (wn + i * 16 + fr) * 64 + fslot;
    }

    f32x4 acc[4][4] = {};

    for (int kt = 0; kt < DD; kt += 32) {
        __syncthreads();
        gload_lds16(Ah + gA0 + kt, lAh0);
        gload_lds16(Ah + gA1 + kt, lAh1);
        gload_lds16(Al + gA0 + kt, lAl0);
        gload_lds16(Al + gA1 + kt, lAl1);
        gload_lds16(Bh + gB0 + kt, lBh0);
        gload_lds16(Bh + gB1 + kt, lBh1);
        gload_lds16(Bl + gB0 + kt, lBl0);
        gload_lds16(Bl + gB1 + kt, lBl1);
        asm volatile("s_waitcnt vmcnt(0)" ::: "memory");
        __syncthreads();

        bf16x8 ah[4], al[4], bh[4], bl[4];
#pragma unroll
        for (int i = 0; i < 4; ++i) {
            ah[i] = *(const bf16x8*)((const char*)sAh + offA[i]);
            al[i] = *(const bf16x8*)((const char*)sAl + offA[i]);
            bh[i] = *(const bf16x8*)((const char*)sBh + offB[i]);
            bl[i] = *(const bf16x8*)((const char*)sBl + offB[i]);
        }
#pragma unroll
        for (int mi = 0; mi < 4; ++mi)
#pragma unroll
            for (int ni = 0; ni < 4; ++ni) {
                acc[mi][ni] = __builtin_amdgcn_mfma_f32_16x16x32_bf16(al[mi], bh[ni], acc[mi][ni], 0, 0, 0);
                acc[mi][ni] = __builtin_amdgcn_mfma_f32_16x16x32_bf16(ah[mi], bl[ni], acc[mi][ni], 0, 0, 0);
                acc[mi][ni] = __builtin_amdgcn_mfma_f32_16x16x32_bf16(ah[mi], bh[ni], acc[mi][ni], 0, 0, 0);
            }
    }

    const int erow = (lane >> 4) * 4;
#pragma unroll
    for (int mi = 0; mi < 4; ++mi)
#pragma unroll
        for (int ni = 0; ni < 4; ++ni) {
            const int r0 = m0 + wm + mi * 16 + erow;
            const int col = n0 + wn + ni * 16 + fr;
            const float bv = bias ? bias[col] : 0.0f;
#pragma unroll
            for (int r = 0; r < 4; ++r) {
                const size_t idx = (size_t)(r0 + r) * DD + col;
                C[idx] = acc[mi][ni][r] + bv;
            }
        }
}

// ---------------- dual small GEMM + fused pointwise epilogue.
//   gate_pre = gatep[idx] (x-part incl. gate_b) + inter @ gwi^T
//   cand_pre = inter @ cw^T + cand_b
//   h = sigmoid(gate_pre)*gelu(cand_pre) + (1-sigmoid)*x   -> hout (fp32 plane)
__global__ __launch_bounds__(256, 2)
void gemm_small_dual(const unsigned short* __restrict__ Ah, const unsigned short* __restrict__ Al,
                     const unsigned short* __restrict__ Gh, const unsigned short* __restrict__ Gl,
                     const unsigned short* __restrict__ Wh, const unsigned short* __restrict__ Wl,
                     const float* __restrict__ gatep, const float* __restrict__ cbias,
                     const float* __restrict__ x, int nbase, float* __restrict__ hout)
{
    __shared__ alignas(16) unsigned short sAh[128 * 32];
    __shared__ alignas(16) unsigned short sAl[128 * 32];
    __shared__ alignas(16) unsigned short sGh[128 * 32];
    __shared__ alignas(16) unsigned short sGl[128 * 32];
    __shared__ alignas(16) unsigned short sWh[128 * 32];
    __shared__ alignas(16) unsigned short sWl[128 * 32];

    const int tid = threadIdx.x;
    const int lane = tid & 63;
    const int w = tid >> 6;

    const int lin = blockIdx.x + (blockIdx.y << 2);
    const int swz = (lin & 7) * 64 + (lin >> 3);
    const int n0 = (swz & 3) * 128;
    const int m0 = (swz >> 2) * 128;

    const int c0 = w * 2, c1 = c0 + 1;
    const int u2 = lane >> 2;
    const int sst = (u2 + (u2 >> 2)) & 3;
    const int kc = (lane & 3) ^ sst;
    const size_t gA0 = (size_t)(m0 + c0 * 16 + u2) * DD + kc * 8;
    const size_t gA1 = (size_t)(m0 + c1 * 16 + u2) * DD + kc * 8;
    const size_t gB0 = (size_t)(n0 + c0 * 16 + u2) * DD + kc * 8;
    const size_t gB1 = (size_t)(n0 + c1 * 16 + u2) * DD + kc * 8;

    const int wm = (w & 1) * 64, wn = (w >> 1) * 64;
    const int fr = lane & 15;
    const int sf = (fr + (fr >> 2)) & 3;
    const int fslot = ((lane >> 4) ^ sf) * 16;
    int offA[4], offB[4];
#pragma unroll
    for (int i = 0; i < 4; ++i) {
        offA[i] = (wm + i * 16 + fr) * 64 + fslot;
        offB[i] = (wn + i * 16 + fr) * 64 + fslot;
    }

    f32x4 accG[4][4] = {};
    f32x4 accC[4][4] = {};

    for (int kt = 0; kt < DD; kt += 32) {
        __syncthreads();
        gload_lds16(Ah + gA0 + kt, sAh + c0 * 512);
        gload_lds16(Ah + gA1 + kt, sAh + c1 * 512);
        gload_lds16(Al + gA0 + kt, sAl + c0 * 512);
        gload_lds16(Al + gA1 + kt, sAl + c1 * 512);
        gload_lds16(Gh + gB0 + kt, sGh + c0 * 512);
        gload_lds16(Gh + gB1 + kt, sGh + c1 * 512);
        gload_lds16(Gl + gB0 + kt, sGl + c0 * 512);
        gload_lds16(Gl + gB1 + kt, sGl + c1 * 512);
        gload_lds16(Wh + gB0 + kt, sWh + c0 * 512);
        gload_lds16(Wh + gB1 + kt, sWh + c1 * 512);
        gload_lds16(Wl + gB0 + kt, sWl + c0 * 512);
        gload_lds16(Wl + gB1 + kt, sWl + c1 * 512);
        asm volatile("s_waitcnt vmcnt(0)" ::: "memory");
        __syncthreads();

        bf16x8 ah[4], al[4], bh[4], bl[4];
#pragma unroll
        for (int i = 0; i < 4; ++i) {
            ah[i] = *(const bf16x8*)((const char*)sAh + offA[i]);
            al[i] = *(const bf16x8*)((const char*)sAl + offA[i]);
        }
#pragma unroll
        for (int i = 0; i < 4; ++i) {
            bh[i] = *(const bf16x8*)((const char*)sGh + offB[i]);
            bl[i] = *(const bf16x8*)((const char*)sGl + offB[i]);
        }
#pragma unroll
        for (int mi = 0; mi < 4; ++mi)
#pragma unroll
            for (int ni = 0; ni < 4; ++ni) {
                accG[mi][ni] = __builtin_amdgcn_mfma_f32_16x16x32_bf16(al[mi], bh[ni], accG[mi][ni], 0, 0, 0);
                accG[mi][ni] = __builtin_amdgcn_mfma_f32_16x16x32_bf16(ah[mi], bl[ni], accG[mi][ni], 0, 0, 0);
                accG[mi][ni] = __builtin_amdgcn_mfma_f32_16x16x32_bf16(ah[mi], bh[ni], accG[mi][ni], 0, 0, 0);
            }
#pragma unroll
        for (int i = 0; i < 4; ++i) {
            bh[i] = *(const bf16x8*)((const char*)sWh + offB[i]);
            bl[i] = *(const bf16x8*)((const char*)sWl + offB[i]);
        }
#pragma unroll
        for (int mi = 0; mi < 4; ++mi)
#pragma unroll
            for (int ni = 0; ni < 4; ++ni) {
                accC[mi][ni] = __builtin_amdgcn_mfma_f32_16x16x32_bf16(al[mi], bh[ni], accC[mi][ni], 0, 0, 0);
                accC[mi][ni] = __builtin_amdgcn_mfma_f32_16x16x32_bf16(ah[mi], bl[ni], accC[mi][ni], 0, 0, 0);
                accC[mi][ni] = __builtin_amdgcn_mfma_f32_16x16x32_bf16(ah[mi], bh[ni], accC[mi][ni], 0, 0, 0);
            }
    }

    // fused pointwise epilogue: h = gate*cand + (1-gate)*x
    const int erow = (lane >> 4) * 4;
#pragma unroll
    for (int mi = 0; mi < 4; ++mi)
#pragma unroll
        for (int ni = 0; ni < 4; ++ni) {
            const int r0 = m0 + wm + mi * 16 + erow;
            const int col = n0 + wn + ni * 16 + fr;
            const float cb = cbias[col];
#pragma unroll
            for (int r = 0; r < 4; ++r) {
                const int lr = r0 + r;                       // local slab row
                const int bb = lr >> 11, ii = lr & (SLAB - 1);
                const size_t idx = (size_t)lr * DD + col;
                const size_t gidx = ((size_t)(bb << 12) + nbase + ii) * DD + col;
                float gpre = gatep[idx] + accG[mi][ni][r];
                float cpre = accC[mi][ni][r] + cb;
                float gate = 1.0f / (1.0f + expf(-gpre));
                float cand = 0.5f * cpre * (1.0f + erff(cpre * 0.70710678118654752440f));
                hout[idx] = gate * cand + (1.0f - gate) * x[gidx];
            }
        }
}

// ---------------- LN + weighted accumulate (+energy at c==1); reads fused h
__global__ __launch_bounds__(128)
void pw_slab(const float* __restrict__ h_, const float* __restrict__ lg,
             const float* __restrict__ lb, const float* __restrict__ cmix,
             int c, int nbase, float* __restrict__ out, float* __restrict__ energy)
{
    __shared__ float sm[4];
    const int rloc = blockIdx.x;                       // 0..16383
    const int b = rloc >> 11, ii = rloc & (SLAB - 1);
    const int grow = (b << 12) + nbase + ii;           // global row
    const int tid = threadIdx.x;
    const size_t lbase = (size_t)rloc * DD + tid * 4;
    const size_t gbase = (size_t)grow * DD + tid * 4;

    float4 h4 = *(const float4*)(h_ + lbase);
    float h[4] = {h4.x, h4.y, h4.z, h4.w};

    const int lane = tid & 63, wid = tid >> 6;
    float s = h[0] + h[1] + h[2] + h[3];
#pragma unroll
    for (int off = 32; off > 0; off >>= 1) s += __shfl_xor(s, off, 64);
    if (lane == 0) sm[wid] = s;
    __syncthreads();
    float mu = (sm[0] + sm[1]) * (1.0f / 512.0f);
    float vs = 0.0f;
#pragma unroll
    for (int j = 0; j < 4; ++j) { float d = h[j] - mu; vs += d * d; }
#pragma unroll
    for (int off = 32; off > 0; off >>= 1) vs += __shfl_xor(vs, off, 64);
    if (lane == 0) sm[2 + wid] = vs;
    __syncthreads();
    float var = (sm[2] + sm[3]) * (1.0f / 512.0f);
    float rstd = 1.0f / sqrtf(var + 1e-5f);

    float m0 = cmix[0], m1 = cmix[1];
    float mx = fmaxf(m0, m1);
    float e0 = expf(m0 - mx), e1 = expf(m1 - mx);
    float wgt = ((c == 0) ? e0 : e1) / (e0 + e1);

    const int dix = tid * 4;
    float4 lg4 = *(const float4*)(lg + dix);
    float4 lb4 = *(const float4*)(lb + dix);
    float lgv[4] = {lg4.x, lg4.y, lg4.z, lg4.w};
    float lbv[4] = {lb4.x, lb4.y, lb4.z, lb4.w};
    float ov[4];
    if (c == 0) {
#pragma unroll
        for (int j = 0; j < 4; ++j)
            ov[j] = wgt * ((h[j] - mu) * rstd * lgv[j] + lbv[j]);
    } else {
        float4 o4 = *(const float4*)(out + gbase);
        ov[0] = o4.x; ov[1] = o4.y; ov[2] = o4.z; ov[3] = o4.w;
#pragma unroll
        for (int j = 0; j < 4; ++j)
            ov[j] += wgt * ((h[j] - mu) * rstd * lgv[j] + lbv[j]);
    }
    float4 st = {ov[0], ov[1], ov[2], ov[3]};
    *(float4*)(out + gbase) = st;

    if (c == 1) {
        // energy = ||out row||
        float s2 = ov[0] * ov[0] + ov[1] * ov[1] + ov[2] * ov[2] + ov[3] * ov[3];
#pragma unroll
        for (int off = 32; off > 0; off >>= 1) s2 += __shfl_xor(s2, off, 64);
        __syncthreads();
        if (lane == 0) sm[wid] = s2;
        __syncthreads();
        if (tid == 0) energy[grow] = sqrtf(sm[0] + sm[1]);
    }
}

// ---------------- per-batch top-k radix select; writes mask IN-PLACE over energy
__global__ __launch_bounds__(1024)
void topk_kernel(float* __restrict__ energy, const int* __restrict__ kptr)
{
    __shared__ unsigned keys[NN];
    __shared__ int hist[256];
    __shared__ int wsum[16];
    __shared__ unsigned sh_pfx;
    __shared__ int sh_need;

    const int b = blockIdx.x, tid = threadIdx.x;
    float* e = energy + (size_t)b * NN;
    for (int n = tid; n < NN; n += 1024) keys[n] = __float_as_uint(e[n]);
    const int K = *kptr;
    if (tid == 0) { sh_pfx = 0u; sh_need = K; }
    __syncthreads();

    for (int round = 0; round < 4; ++round) {
        const int shift = 24 - 8 * round;
        if (tid < 256) hist[tid] = 0;
        __syncthreads();
        const unsigned pfx = sh_pfx;
        const unsigned mhi = (round == 0) ? 0u : (0xFFFFFFFFu << (shift + 8));
        for (int n = tid; n < NN; n += 1024) {
            unsigned kv = keys[n];
            if ((kv & mhi) == pfx) atomicAdd(&hist[(kv >> shift) & 255], 1);
        }
        __syncthreads();
        if (tid == 0) {
            int need = sh_need;
            int d = 255;
            for (;; --d) {
                int cct = hist[d];
                if (need <= cct) break;
                need -= cct;
            }
            sh_pfx = pfx | ((unsigned)d << shift);
            sh_need = need;
        }
        __syncthreads();
    }

    const unsigned T = sh_pfx;
    const int need = sh_need;

    const int n0 = tid * 4;
    unsigned kv[4]; int eq[4]; int loc[4];
    int s = 0;
#pragma unroll
    for (int j = 0; j < 4; ++j) {
        kv[j] = keys[n0 + j];
        eq[j] = (kv[j] == T) ? 1 : 0;
        loc[j] = s; s += eq[j];
    }
    const int lane = tid & 63, wid = tid >> 6;
    int v = s;
#pragma unroll
    for (int off = 1; off < 64; off <<= 1) {
        int u = __shfl_up(v, off, 64);
        if (lane >= off) v += u;
    }
    if (lane == 63) wsum[wid] = v;
    __syncthreads();
    if (tid == 0) {
        int acc = 0;
        for (int w2 = 0; w2 < 16; ++w2) { int t = wsum[w2]; wsum[w2] = acc; acc += t; }
    }
    __syncthreads();
    const int base = wsum[wid] + (v - s);
    const float scale = (float)(4096.0 / (double)K);
#pragma unroll
    for (int j = 0; j < 4; ++j) {
        bool sel = (kv[j] > T) || (eq[j] && (base + loc[j]) < need);
        e[n0 + j] = sel ? scale : 0.0f;
    }
}

__global__ __launch_bounds__(128)
void mask_kernel(float* __restrict__ out, const float* __restrict__ mscale)
{
    const int row = blockIdx.x;
    const int tid = threadIdx.x;
    const size_t base = (size_t)row * DD + tid * 4;
    const float sc = mscale[row];
    float4 v = *(const float4*)(out + base);
    v.x *= sc; v.y *= sc; v.z *= sc; v.w *= sc;
    *(float4*)(out + base) = v;
}

extern "C" void kernel_launch(void* const* d_in, const int* in_sizes, int n_in,
                              void* d_out, int out_size, void* d_ws, size_t ws_size,
                              hipStream_t stream)
{
    const float* x      = (const float*)d_in[0];
    const float* net    = (const float*)d_in[1];
    const float* gate_w = (const float*)d_in[2];
    const float* gate_b = (const float*)d_in[3];
    const float* cand_w = (const float*)d_in[4];
    const float* cand_b = (const float*)d_in[5];
    const float* ln_g   = (const float*)d_in[6];
    const float* ln_b   = (const float*)d_in[7];
    const float* cmix   = (const float*)d_in[8];
    const int*   kptr   = (const int*)d_in[9];
    float* out = (float*)d_out;

    const size_t ROWS  = (size_t)BB * NN;      // 32768
    const size_t PLANE = ROWS * DD;            // 16,777,216 elems

    // Workspace carve — total 201,457,664 B (<= proven 201,588,736):
    //   Slot A: xT hi/lo bf16 [b][d][n]                 67,108,864
    //   Slot N: net slab split (2048x4096 hi+lo)        33,554,432
    //           (reused for weight splits after gemm_big frees it)
    //   Slot I: inter slab split [16384][512] hi+lo     33,554,432
    //   Slot X: x slab split hi+lo -> h fp32            33,554,432
    //   Slot G: gatep fp32 [16384][512]                 33,554,432
    //   energy [32768] fp32 (topk writes mask in-place)    131,072
    char* p = (char*)d_ws;
    unsigned short* xTh = (unsigned short*)p;             p += PLANE * 2;
    unsigned short* xTl = (unsigned short*)p;             p += PLANE * 2;
    char* slotN = p;                                      p += (size_t)SLAB * NN * 2 * 2;
    unsigned short* netsh = (unsigned short*)slotN;
    unsigned short* netsl = netsh + (size_t)SLAB * NN;
    unsigned short* cwh = (unsigned short*)slotN;          // weight aliases (post-gemm_big)
    unsigned short* cwl = cwh + 512 * 512;
    unsigned short* gxh = cwl + 512 * 512;
    unsigned short* gxl = gxh + 512 * 512;
    unsigned short* gih = gxl + 512 * 512;
    unsigned short* gil = gih + 512 * 512;
    unsigned short* inth = (unsigned short*)p;            p += (size_t)SROWS * DD * 2;
    unsigned short* intl = (unsigned short*)p;            p += (size_t)SROWS * DD * 2;
    char* slotX = p;                                      p += (size_t)SROWS * DD * 4;
    unsigned short* xsh = (unsigned short*)slotX;
    unsigned short* xsl = xsh + (size_t)SROWS * DD;
    float* hplane = (float*)slotX;                        // alias (post-gate0)
    float* gatep = (float*)p;                             p += (size_t)SROWS * DD * 4;
    float* energy = (float*)p;

    // x -> transposed split planes (once)
    conv_xT<<<dim3(NN / 64, DD / 64, BB), 256, 0, stream>>>(x, xTh, xTl);

    for (int c = 0; c < 2; ++c) {
        for (int s = 0; s < 2; ++s) {
            const int nbase = s * SLAB;
            // net slab -> split planes
            conv_split<<<(SLAB * NN / 4) / 256, 256, 0, stream>>>(
                net + (size_t)c * NN * NN + (size_t)nbase * NN, netsh, netsl);
            // inter slab = net_slab @ x   (split-3 MFMA)
            gemm_big<<<dim3(DD / 128, BB, SLAB / 128), 256, 0, stream>>>(
                netsh, netsl, xTh, xTl, inth, intl);
            // weights -> split planes (into slot N, now free)
            conv_w3<<<768, 256, 0, stream>>>(
                cand_w + (size_t)c * DD * DD, gate_w + (size_t)c * DD * 2 * DD,
                cwh, cwl, gxh, gxl, gih, gil);
            // x slab -> split planes
            conv_xs<<<(SROWS * DD / 4) / 256, 256, 0, stream>>>(x, nbase, xsh, xsl);
            // gate_pre(x part) = x @ gwx^T + gate_b  (reads xs; precedes h overwrite)
            gemm_small<<<dim3(4, SROWS / 128), 256, 0, stream>>>(
                xsh, xsl, gxh, gxl, gate_b + (size_t)c * DD, gatep);
            // fused: gate/cand GEMMs + pointwise -> h (overwrites xs slot)
            gemm_small_dual<<<dim3(4, SROWS / 128), 256, 0, stream>>>(
                inth, intl, gih, gil, cwh, cwl, gatep, cand_b + (size_t)c * DD,
                x, nbase, hplane);
            // LN + weighted accumulate (+energy at c==1)
            pw_slab<<<SROWS, 128, 0, stream>>>(
                hplane, ln_g + (size_t)c * DD, ln_b + (size_t)c * DD,
                cmix, c, nbase, out, energy);
        }
    }

    topk_kernel<<<BB, 1024, 0, stream>>>(energy, kptr);
    mask_kernel<<<(int)ROWS, 128, 0, stream>>>(out, energy);
}

// Round 8
// 1649.330 us; speedup vs baseline: 1.1047x; 1.0158x over previous
//
#include <hip/hip_runtime.h>
#include <hip/hip_bf16.h>
#include <math.h>

#define BB 8
#define NN 4096
#define DD 512
#define SLAB 2048                  // agents per slab
#define SROWS (BB * SLAB)          // 16384 rows per slab

typedef short bf16x8 __attribute__((ext_vector_type(8)));
typedef float f32x4 __attribute__((ext_vector_type(4)));

#define AS1 __attribute__((address_space(1)))
#define AS3 __attribute__((address_space(3)))

__device__ __forceinline__ void gload_lds16(const void* g, void* l) {
    __builtin_amdgcn_global_load_lds((const AS1 unsigned int*)g,
                                     (AS3 unsigned int*)l, 16, 0, 0);
}

__device__ __forceinline__ void split_bf16(float v, unsigned short& h, unsigned short& l) {
    __hip_bfloat16 bh = __float2bfloat16(v);         // RNE
    float hf = __bfloat162float(bh);
    __hip_bfloat16 bl = __float2bfloat16(v - hf);
    h = *reinterpret_cast<unsigned short*>(&bh);
    l = *reinterpret_cast<unsigned short*>(&bl);
}

// ---------------- generic contiguous split conv (used for net slabs)
__global__ __launch_bounds__(256)
void conv_split(const float* __restrict__ src, unsigned short* __restrict__ hi,
                unsigned short* __restrict__ lo)
{
    const size_t i = (size_t)blockIdx.x * 256 + threadIdx.x;   // float4 index
    float4 v = ((const float4*)src)[i];
    ushort4 h, l;
    split_bf16(v.x, h.x, l.x);
    split_bf16(v.y, h.y, l.y);
    split_bf16(v.z, h.z, l.z);
    split_bf16(v.w, h.w, l.w);
    ((ushort4*)hi)[i] = h;
    ((ushort4*)lo)[i] = l;
}

// ---------------- fused weight split: cand_w[c] + gate_w[c] x-part + inter-part
__global__ __launch_bounds__(256)
void conv_w3(const float* __restrict__ cw, const float* __restrict__ gw,
             unsigned short* __restrict__ cwh, unsigned short* __restrict__ cwl,
             unsigned short* __restrict__ gxh, unsigned short* __restrict__ gxl,
             unsigned short* __restrict__ gih, unsigned short* __restrict__ gil)
{
    const int blk = blockIdx.x;                 // 0..767
    const int i = (blk & 255) * 256 + threadIdx.x;   // 0..65535 float4 index
    const int n = i >> 7, kq = (i & 127) * 4;
    const float* src;
    unsigned short *oh, *ol;
    if (blk < 256)      { src = cw + (size_t)n * 512 + kq;        oh = cwh; ol = cwl; }
    else if (blk < 512) { src = gw + (size_t)n * 1024 + kq;       oh = gxh; ol = gxl; }
    else                { src = gw + (size_t)n * 1024 + 512 + kq; oh = gih; ol = gil; }
    float4 v = *(const float4*)src;
    ushort4 h, l;
    split_bf16(v.x, h.x, l.x);
    split_bf16(v.y, h.y, l.y);
    split_bf16(v.z, h.z, l.z);
    split_bf16(v.w, h.w, l.w);
    *(ushort4*)(oh + (size_t)n * 512 + kq) = h;
    *(ushort4*)(ol + (size_t)n * 512 + kq) = l;
}

// ---------------- x slab rows -> split planes [16384][512]
__global__ __launch_bounds__(256)
void conv_xs(const float* __restrict__ x, int nbase,
             unsigned short* __restrict__ hi, unsigned short* __restrict__ lo)
{
    const size_t i = (size_t)blockIdx.x * 256 + threadIdx.x;   // float4 idx, 2,097,152
    const int r = (int)(i >> 7), kq = (int)(i & 127) * 4;
    const int b = r >> 11, ii = r & (SLAB - 1);
    float4 v = *(const float4*)(x + ((size_t)(b << 12) + nbase + ii) * DD + kq);
    ushort4 h, l;
    split_bf16(v.x, h.x, l.x);
    split_bf16(v.y, h.y, l.y);
    split_bf16(v.z, h.z, l.z);
    split_bf16(v.w, h.w, l.w);
    *(ushort4*)(hi + (size_t)r * DD + kq) = h;
    *(ushort4*)(lo + (size_t)r * DD + kq) = l;
}

// ---------------- conversion + transpose: x fp32 [b][n][d] -> xT hi/lo bf16 [b][d][n]
__global__ __launch_bounds__(256)
void conv_xT(const float* __restrict__ x, unsigned short* __restrict__ th,
             unsigned short* __restrict__ tl)
{
    __shared__ unsigned short Th[64][65];
    __shared__ unsigned short Tl[64][65];
    const int n0 = blockIdx.x * 64, d0 = blockIdx.y * 64, b = blockIdx.z;
    const int t = threadIdx.x;
    const int r = t >> 4, c4 = (t & 15) * 4;
#pragma unroll
    for (int i = 0; i < 4; ++i) {
        int row = r + i * 16;
        float4 v = *(const float4*)(x + ((size_t)b * NN + n0 + row) * DD + d0 + c4);
        split_bf16(v.x, Th[row][c4 + 0], Tl[row][c4 + 0]);
        split_bf16(v.y, Th[row][c4 + 1], Tl[row][c4 + 1]);
        split_bf16(v.z, Th[row][c4 + 2], Tl[row][c4 + 2]);
        split_bf16(v.w, Th[row][c4 + 3], Tl[row][c4 + 3]);
    }
    __syncthreads();
    const int od = t >> 2;
    const int on0 = (t & 3) * 16;
    unsigned short hb[16], lb[16];
#pragma unroll
    for (int j = 0; j < 16; ++j) { hb[j] = Th[on0 + j][od]; lb[j] = Tl[on0 + j][od]; }
    const size_t obase = ((size_t)b * DD + d0 + od) * (size_t)NN + n0 + on0;
#pragma unroll
    for (int q = 0; q < 4; ++q) {
        ushort4 hv = {hb[q * 4 + 0], hb[q * 4 + 1], hb[q * 4 + 2], hb[q * 4 + 3]};
        ushort4 lv = {lb[q * 4 + 0], lb[q * 4 + 1], lb[q * 4 + 2], lb[q * 4 + 3]};
        *(ushort4*)(th + obase + q * 4) = hv;
        *(ushort4*)(tl + obase + q * 4) = lv;
    }
}

// ---------------- big GEMM (R3-proven): inter_slab = net_slab @ x  (split-3 bf16)
// A planes: [2048][4096] (net slab, k contig). B planes: xT [b][512][4096] (k contig).
// Output: inter slab split planes [b*2048 + m][512].
__global__ __launch_bounds__(256, 2)
void gemm_big(const unsigned short* __restrict__ Ah, const unsigned short* __restrict__ Al,
              const unsigned short* __restrict__ Bh, const unsigned short* __restrict__ Bl,
              unsigned short* __restrict__ Ch, unsigned short* __restrict__ Cl)
{
    __shared__ alignas(16) unsigned short sAh[128 * 32];
    __shared__ alignas(16) unsigned short sAl[128 * 32];
    __shared__ alignas(16) unsigned short sBh[128 * 32];
    __shared__ alignas(16) unsigned short sBl[128 * 32];

    const int tid = threadIdx.x;
    const int lane = tid & 63;
    const int w = tid >> 6;

    // grid (4,8,16) = 512 blocks; XCD-bijective chunking.
    const int lin = blockIdx.x + (blockIdx.y << 2) + (blockIdx.z << 5);
    const int swz = (lin & 7) * 64 + (lin >> 3);
    const int n0 = (swz & 3) * 128;        // d tile (4)
    const int b  = (swz >> 2) & 7;         // batch (8)
    const int m0 = (swz >> 5) * 128;       // local agent tile (16)

    Bh += (size_t)b * DD * NN;
    Bl += (size_t)b * DD * NN;

    const int c0 = w * 2, c1 = c0 + 1;
    const int u2 = lane >> 2;
    const int sst = (u2 + (u2 >> 2)) & 3;
    const int kc = (lane & 3) ^ sst;
    const size_t gA0 = (size_t)(m0 + c0 * 16 + u2) * NN + kc * 8;
    const size_t gA1 = (size_t)(m0 + c1 * 16 + u2) * NN + kc * 8;
    const size_t gB0 = (size_t)(n0 + c0 * 16 + u2) * NN + kc * 8;
    const size_t gB1 = (size_t)(n0 + c1 * 16 + u2) * NN + kc * 8;
    unsigned short* lAh0 = sAh + c0 * 512; unsigned short* lAh1 = sAh + c1 * 512;
    unsigned short* lAl0 = sAl + c0 * 512; unsigned short* lAl1 = sAl + c1 * 512;
    unsigned short* lBh0 = sBh + c0 * 512; unsigned short* lBh1 = sBh + c1 * 512;
    unsigned short* lBl0 = sBl + c0 * 512; unsigned short* lBl1 = sBl + c1 * 512;

    const int wm = (w & 1) * 64, wn = (w >> 1) * 64;
    const int fr = lane & 15;
    const int sf = (fr + (fr >> 2)) & 3;
    const int fslot = ((lane >> 4) ^ sf) * 16;
    int offA[4], offB[4];
#pragma unroll
    for (int i = 0; i < 4; ++i) {
        offA[i] = (wm + i * 16 + fr) * 64 + fslot;
        offB[i] = (wn + i * 16 + fr) * 64 + fslot;
    }

    f32x4 acc[4][4] = {};

    for (int kt = 0; kt < NN; kt += 32) {
        __syncthreads();
        gload_lds16(Ah + gA0 + kt, lAh0);
        gload_lds16(Ah + gA1 + kt, lAh1);
        gload_lds16(Al + gA0 + kt, lAl0);
        gload_lds16(Al + gA1 + kt, lAl1);
        gload_lds16(Bh + gB0 + kt, lBh0);
        gload_lds16(Bh + gB1 + kt, lBh1);
        gload_lds16(Bl + gB0 + kt, lBl0);
        gload_lds16(Bl + gB1 + kt, lBl1);
        asm volatile("s_waitcnt vmcnt(0)" ::: "memory");
        __syncthreads();

        bf16x8 ah[4], al[4], bh[4], bl[4];
#pragma unroll
        for (int i = 0; i < 4; ++i) {
            ah[i] = *(const bf16x8*)((const char*)sAh + offA[i]);
            al[i] = *(const bf16x8*)((const char*)sAl + offA[i]);
            bh[i] = *(const bf16x8*)((const char*)sBh + offB[i]);
            bl[i] = *(const bf16x8*)((const char*)sBl + offB[i]);
        }
#pragma unroll
        for (int mi = 0; mi < 4; ++mi)
#pragma unroll
            for (int ni = 0; ni < 4; ++ni) {
                acc[mi][ni] = __builtin_amdgcn_mfma_f32_16x16x32_bf16(al[mi], bh[ni], acc[mi][ni], 0, 0, 0);
                acc[mi][ni] = __builtin_amdgcn_mfma_f32_16x16x32_bf16(ah[mi], bl[ni], acc[mi][ni], 0, 0, 0);
                acc[mi][ni] = __builtin_amdgcn_mfma_f32_16x16x32_bf16(ah[mi], bh[ni], acc[mi][ni], 0, 0, 0);
            }
    }

    // epilogue: write inter slab as split bf16 planes. row = b*2048 + local m.
    const int erow = (lane >> 4) * 4;
#pragma unroll
    for (int mi = 0; mi < 4; ++mi)
#pragma unroll
        for (int ni = 0; ni < 4; ++ni) {
            const int r0 = m0 + wm + mi * 16 + erow;
            const int col = n0 + wn + ni * 16 + fr;
#pragma unroll
            for (int r = 0; r < 4; ++r) {
                unsigned short h, l;
                split_bf16(acc[mi][ni][r], h, l);
                const size_t idx = ((size_t)b * SLAB + r0 + r) * DD + col;
                Ch[idx] = h;
                Cl[idx] = l;
            }
        }
}

// ---------------- fused gate/cand GEMMs + pointwise epilogue.
// Phase 1 (K=512): accG  = xs    @ gwx^T          (A=xs planes)
// Phase 2 (K=512): accG += inter @ gwi^T,  accC = inter @ cw^T
// Epilogue: gpre = accG + gate_b; cpre = accC + cand_b;
//           h = sigmoid(gpre)*gelu(cpre) + (1-sigmoid)*x  -> hout (slot G)
__global__ __launch_bounds__(256, 2)
void gemm_fused(const unsigned short* __restrict__ Xh, const unsigned short* __restrict__ Xl,
                const unsigned short* __restrict__ Ih, const unsigned short* __restrict__ Il,
                const unsigned short* __restrict__ GXh, const unsigned short* __restrict__ GXl,
                const unsigned short* __restrict__ GIh, const unsigned short* __restrict__ GIl,
                const unsigned short* __restrict__ CWh, const unsigned short* __restrict__ CWl,
                const float* __restrict__ gbias, const float* __restrict__ cbias,
                const float* __restrict__ x, int nbase, float* __restrict__ hout)
{
    __shared__ alignas(16) unsigned short sAh[128 * 32];
    __shared__ alignas(16) unsigned short sAl[128 * 32];
    __shared__ alignas(16) unsigned short sBh[128 * 32];
    __shared__ alignas(16) unsigned short sBl[128 * 32];
    __shared__ alignas(16) unsigned short sWh[128 * 32];
    __shared__ alignas(16) unsigned short sWl[128 * 32];

    const int tid = threadIdx.x;
    const int lane = tid & 63;
    const int w = tid >> 6;

    const int lin = blockIdx.x + (blockIdx.y << 2);
    const int swz = (lin & 7) * 64 + (lin >> 3);
    const int n0 = (swz & 3) * 128;
    const int m0 = (swz >> 2) * 128;

    const int c0 = w * 2, c1 = c0 + 1;
    const int u2 = lane >> 2;
    const int sst = (u2 + (u2 >> 2)) & 3;
    const int kc = (lane & 3) ^ sst;
    const size_t gA0 = (size_t)(m0 + c0 * 16 + u2) * DD + kc * 8;
    const size_t gA1 = (size_t)(m0 + c1 * 16 + u2) * DD + kc * 8;
    const size_t gB0 = (size_t)(n0 + c0 * 16 + u2) * DD + kc * 8;
    const size_t gB1 = (size_t)(n0 + c1 * 16 + u2) * DD + kc * 8;
    unsigned short* lAh0 = sAh + c0 * 512; unsigned short* lAh1 = sAh + c1 * 512;
    unsigned short* lAl0 = sAl + c0 * 512; unsigned short* lAl1 = sAl + c1 * 512;
    unsigned short* lBh0 = sBh + c0 * 512; unsigned short* lBh1 = sBh + c1 * 512;
    unsigned short* lBl0 = sBl + c0 * 512; unsigned short* lBl1 = sBl + c1 * 512;
    unsigned short* lWh0 = sWh + c0 * 512; unsigned short* lWh1 = sWh + c1 * 512;
    unsigned short* lWl0 = sWl + c0 * 512; unsigned short* lWl1 = sWl + c1 * 512;

    const int wm = (w & 1) * 64, wn = (w >> 1) * 64;
    const int fr = lane & 15;
    const int sf = (fr + (fr >> 2)) & 3;
    const int fslot = ((lane >> 4) ^ sf) * 16;
    int offA[4], offB[4];
#pragma unroll
    for (int i = 0; i < 4; ++i) {
        offA[i] = (wm + i * 16 + fr) * 64 + fslot;
        offB[i] = (wn + i * 16 + fr) * 64 + fslot;
    }

    f32x4 accG[4][4] = {};
    f32x4 accC[4][4] = {};

    // ---- phase 1: A = xs, B = gwx -> accG
    for (int kt = 0; kt < DD; kt += 32) {
        __syncthreads();
        gload_lds16(Xh + gA0 + kt, lAh0);
        gload_lds16(Xh + gA1 + kt, lAh1);
        gload_lds16(Xl + gA0 + kt, lAl0);
        gload_lds16(Xl + gA1 + kt, lAl1);
        gload_lds16(GXh + gB0 + kt, lBh0);
        gload_lds16(GXh + gB1 + kt, lBh1);
        gload_lds16(GXl + gB0 + kt, lBl0);
        gload_lds16(GXl + gB1 + kt, lBl1);
        asm volatile("s_waitcnt vmcnt(0)" ::: "memory");
        __syncthreads();

        bf16x8 ah[4], al[4], bh[4], bl[4];
#pragma unroll
        for (int i = 0; i < 4; ++i) {
            ah[i] = *(const bf16x8*)((const char*)sAh + offA[i]);
            al[i] = *(const bf16x8*)((const char*)sAl + offA[i]);
            bh[i] = *(const bf16x8*)((const char*)sBh + offB[i]);
            bl[i] = *(const bf16x8*)((const char*)sBl + offB[i]);
        }
#pragma unroll
        for (int mi = 0; mi < 4; ++mi)
#pragma unroll
            for (int ni = 0; ni < 4; ++ni) {
                accG[mi][ni] = __builtin_amdgcn_mfma_f32_16x16x32_bf16(al[mi], bh[ni], accG[mi][ni], 0, 0, 0);
                accG[mi][ni] = __builtin_amdgcn_mfma_f32_16x16x32_bf16(ah[mi], bl[ni], accG[mi][ni], 0, 0, 0);
                accG[mi][ni] = __builtin_amdgcn_mfma_f32_16x16x32_bf16(ah[mi], bh[ni], accG[mi][ni], 0, 0, 0);
            }
    }

    // ---- phase 2: A = inter, B = gwi -> accG ; W = cw -> accC
    for (int kt = 0; kt < DD; kt += 32) {
        __syncthreads();
        gload_lds16(Ih + gA0 + kt, lAh0);
        gload_lds16(Ih + gA1 + kt, lAh1);
        gload_lds16(Il + gA0 + kt, lAl0);
        gload_lds16(Il + gA1 + kt, lAl1);
        gload_lds16(GIh + gB0 + kt, lBh0);
        gload_lds16(GIh + gB1 + kt, lBh1);
        gload_lds16(GIl + gB0 + kt, lBl0);
        gload_lds16(GIl + gB1 + kt, lBl1);
        gload_lds16(CWh + gB0 + kt, lWh0);
        gload_lds16(CWh + gB1 + kt, lWh1);
        gload_lds16(CWl + gB0 + kt, lWl0);
        gload_lds16(CWl + gB1 + kt, lWl1);
        asm volatile("s_waitcnt vmcnt(0)" ::: "memory");
        __syncthreads();

        bf16x8 ah[4], al[4], bh[4], bl[4];
#pragma unroll
        for (int i = 0; i < 4; ++i) {
            ah[i] = *(const bf16x8*)((const char*)sAh + offA[i]);
            al[i] = *(const bf16x8*)((const char*)sAl + offA[i]);
        }
#pragma unroll
        for (int i = 0; i < 4; ++i) {
            bh[i] = *(const bf16x8*)((const char*)sBh + offB[i]);
            bl[i] = *(const bf16x8*)((const char*)sBl + offB[i]);
        }
#pragma unroll
        for (int mi = 0; mi < 4; ++mi)
#pragma unroll
            for (int ni = 0; ni < 4; ++ni) {
                accG[mi][ni] = __builtin_amdgcn_mfma_f32_16x16x32_bf16(al[mi], bh[ni], accG[mi][ni], 0, 0, 0);
                accG[mi][ni] = __builtin_amdgcn_mfma_f32_16x16x32_bf16(ah[mi], bl[ni], accG[mi][ni], 0, 0, 0);
                accG[mi][ni] = __builtin_amdgcn_mfma_f32_16x16x32_bf16(ah[mi], bh[ni], accG[mi][ni], 0, 0, 0);
            }
#pragma unroll
        for (int i = 0; i < 4; ++i) {
            bh[i] = *(const bf16x8*)((const char*)sWh + offB[i]);
            bl[i] = *(const bf16x8*)((const char*)sWl + offB[i]);
        }
#pragma unroll
        for (int mi = 0; mi < 4; ++mi)
#pragma unroll
            for (int ni = 0; ni < 4; ++ni) {
                accC[mi][ni] = __builtin_amdgcn_mfma_f32_16x16x32_bf16(al[mi], bh[ni], accC[mi][ni], 0, 0, 0);
                accC[mi][ni] = __builtin_amdgcn_mfma_f32_16x16x32_bf16(ah[mi], bl[ni], accC[mi][ni], 0, 0, 0);
                accC[mi][ni] = __builtin_amdgcn_mfma_f32_16x16x32_bf16(ah[mi], bh[ni], accC[mi][ni], 0, 0, 0);
            }
    }

    // fused pointwise epilogue: h = gate*cand + (1-gate)*x  -> hout (slot G)
    const int erow = (lane >> 4) * 4;
#pragma unroll
    for (int mi = 0; mi < 4; ++mi)
#pragma unroll
        for (int ni = 0; ni < 4; ++ni) {
            const int r0 = m0 + wm + mi * 16 + erow;
            const int col = n0 + wn + ni * 16 + fr;
            const float gb = gbias[col];
            const float cb = cbias[col];
#pragma unroll
            for (int r = 0; r < 4; ++r) {
                const int lr = r0 + r;                       // local slab row
                const int bb = lr >> 11, ii = lr & (SLAB - 1);
                const size_t idx = (size_t)lr * DD + col;
                const size_t gidx = ((size_t)(bb << 12) + nbase + ii) * DD + col;
                float gpre = accG[mi][ni][r] + gb;
                float cpre = accC[mi][ni][r] + cb;
                float gate = 1.0f / (1.0f + expf(-gpre));
                float cand = 0.5f * cpre * (1.0f + erff(cpre * 0.70710678118654752440f));
                hout[idx] = gate * cand + (1.0f - gate) * x[gidx];
            }
        }
}

// ---------------- LN + weighted accumulate (+energy at c==1); reads fused h
__global__ __launch_bounds__(128)
void pw_slab(const float* __restrict__ h_, const float* __restrict__ lg,
             const float* __restrict__ lb, const float* __restrict__ cmix,
             int c, int nbase, float* __restrict__ out, float* __restrict__ energy)
{
    __shared__ float sm[4];
    const int rloc = blockIdx.x;                       // 0..16383
    const int b = rloc >> 11, ii = rloc & (SLAB - 1);
    const int grow = (b << 12) + nbase + ii;           // global row
    const int tid = threadIdx.x;
    const size_t lbase = (size_t)rloc * DD + tid * 4;
    const size_t gbase = (size_t)grow * DD + tid * 4;

    float4 h4 = *(const float4*)(h_ + lbase);
    float h[4] = {h4.x, h4.y, h4.z, h4.w};

    const int lane = tid & 63, wid = tid >> 6;
    float s = h[0] + h[1] + h[2] + h[3];
#pragma unroll
    for (int off = 32; off > 0; off >>= 1) s += __shfl_xor(s, off, 64);
    if (lane == 0) sm[wid] = s;
    __syncthreads();
    float mu = (sm[0] + sm[1]) * (1.0f / 512.0f);
    float vs = 0.0f;
#pragma unroll
    for (int j = 0; j < 4; ++j) { float d = h[j] - mu; vs += d * d; }
#pragma unroll
    for (int off = 32; off > 0; off >>= 1) vs += __shfl_xor(vs, off, 64);
    if (lane == 0) sm[2 + wid] = vs;
    __syncthreads();
    float var = (sm[2] + sm[3]) * (1.0f / 512.0f);
    float rstd = 1.0f / sqrtf(var + 1e-5f);

    float m0 = cmix[0], m1 = cmix[1];
    float mx = fmaxf(m0, m1);
    float e0 = expf(m0 - mx), e1 = expf(m1 - mx);
    float wgt = ((c == 0) ? e0 : e1) / (e0 + e1);

    const int dix = tid * 4;
    float4 lg4 = *(const float4*)(lg + dix);
    float4 lb4 = *(const float4*)(lb + dix);
    float lgv[4] = {lg4.x, lg4.y, lg4.z, lg4.w};
    float lbv[4] = {lb4.x, lb4.y, lb4.z, lb4.w};
    float ov[4];
    if (c == 0) {
#pragma unroll
        for (int j = 0; j < 4; ++j)
            ov[j] = wgt * ((h[j] - mu) * rstd * lgv[j] + lbv[j]);
    } else {
        float4 o4 = *(const float4*)(out + gbase);
        ov[0] = o4.x; ov[1] = o4.y; ov[2] = o4.z; ov[3] = o4.w;
#pragma unroll
        for (int j = 0; j < 4; ++j)
            ov[j] += wgt * ((h[j] - mu) * rstd * lgv[j] + lbv[j]);
    }
    float4 st = {ov[0], ov[1], ov[2], ov[3]};
    *(float4*)(out + gbase) = st;

    if (c == 1) {
        // energy = ||out row||
        float s2 = ov[0] * ov[0] + ov[1] * ov[1] + ov[2] * ov[2] + ov[3] * ov[3];
#pragma unroll
        for (int off = 32; off > 0; off >>= 1) s2 += __shfl_xor(s2, off, 64);
        __syncthreads();
        if (lane == 0) sm[wid] = s2;
        __syncthreads();
        if (tid == 0) energy[grow] = sqrtf(sm[0] + sm[1]);
    }
}

// ---------------- per-batch top-k radix select; writes mask IN-PLACE over energy
__global__ __launch_bounds__(1024)
void topk_kernel(float* __restrict__ energy, const int* __restrict__ kptr)
{
    __shared__ unsigned keys[NN];
    __shared__ int hist[256];
    __shared__ int wsum[16];
    __shared__ unsigned sh_pfx;
    __shared__ int sh_need;

    const int b = blockIdx.x, tid = threadIdx.x;
    float* e = energy + (size_t)b * NN;
    for (int n = tid; n < NN; n += 1024) keys[n] = __float_as_uint(e[n]);
    const int K = *kptr;
    if (tid == 0) { sh_pfx = 0u; sh_need = K; }
    __syncthreads();

    for (int round = 0; round < 4; ++round) {
        const int shift = 24 - 8 * round;
        if (tid < 256) hist[tid] = 0;
        __syncthreads();
        const unsigned pfx = sh_pfx;
        const unsigned mhi = (round == 0) ? 0u : (0xFFFFFFFFu << (shift + 8));
        for (int n = tid; n < NN; n += 1024) {
            unsigned kv = keys[n];
            if ((kv & mhi) == pfx) atomicAdd(&hist[(kv >> shift) & 255], 1);
        }
        __syncthreads();
        if (tid == 0) {
            int need = sh_need;
            int d = 255;
            for (;; --d) {
                int cct = hist[d];
                if (need <= cct) break;
                need -= cct;
            }
            sh_pfx = pfx | ((unsigned)d << shift);
            sh_need = need;
        }
        __syncthreads();
    }

    const unsigned T = sh_pfx;
    const int need = sh_need;

    const int n0 = tid * 4;
    unsigned kv[4]; int eq[4]; int loc[4];
    int s = 0;
#pragma unroll
    for (int j = 0; j < 4; ++j) {
        kv[j] = keys[n0 + j];
        eq[j] = (kv[j] == T) ? 1 : 0;
        loc[j] = s; s += eq[j];
    }
    const int lane = tid & 63, wid = tid >> 6;
    int v = s;
#pragma unroll
    for (int off = 1; off < 64; off <<= 1) {
        int u = __shfl_up(v, off, 64);
        if (lane >= off) v += u;
    }
    if (lane == 63) wsum[wid] = v;
    __syncthreads();
    if (tid == 0) {
        int acc = 0;
        for (int w2 = 0; w2 < 16; ++w2) { int t = wsum[w2]; wsum[w2] = acc; acc += t; }
    }
    __syncthreads();
    const int base = wsum[wid] + (v - s);
    const float scale = (float)(4096.0 / (double)K);
#pragma unroll
    for (int j = 0; j < 4; ++j) {
        bool sel = (kv[j] > T) || (eq[j] && (base + loc[j]) < need);
        e[n0 + j] = sel ? scale : 0.0f;
    }
}

__global__ __launch_bounds__(128)
void mask_kernel(float* __restrict__ out, const float* __restrict__ mscale)
{
    const int row = blockIdx.x;
    const int tid = threadIdx.x;
    const size_t base = (size_t)row * DD + tid * 4;
    const float sc = mscale[row];
    float4 v = *(const float4*)(out + base);
    v.x *= sc; v.y *= sc; v.z *= sc; v.w *= sc;
    *(float4*)(out + base) = v;
}

extern "C" void kernel_launch(void* const* d_in, const int* in_sizes, int n_in,
                              void* d_out, int out_size, void* d_ws, size_t ws_size,
                              hipStream_t stream)
{
    const float* x      = (const float*)d_in[0];
    const float* net    = (const float*)d_in[1];
    const float* gate_w = (const float*)d_in[2];
    const float* gate_b = (const float*)d_in[3];
    const float* cand_w = (const float*)d_in[4];
    const float* cand_b = (const float*)d_in[5];
    const float* ln_g   = (const float*)d_in[6];
    const float* ln_b   = (const float*)d_in[7];
    const float* cmix   = (const float*)d_in[8];
    const int*   kptr   = (const int*)d_in[9];
    float* out = (float*)d_out;

    const size_t ROWS  = (size_t)BB * NN;      // 32768
    const size_t PLANE = ROWS * DD;            // 16,777,216 elems

    // Workspace carve — total 201,457,664 B (<= proven 201,588,736):
    //   Slot A: xT hi/lo bf16 [b][d][n]                 67,108,864
    //   Slot N: net slab split (2048x4096 hi+lo)        33,554,432
    //           (reused for weight splits after gemm_big frees it)
    //   Slot I: inter slab split [16384][512] hi+lo     33,554,432
    //   Slot X: x slab split hi+lo (stays live)         33,554,432
    //   Slot G: h fp32 [16384][512]                     33,554,432
    //   energy [32768] fp32 (topk writes mask in-place)    131,072
    char* p = (char*)d_ws;
    unsigned short* xTh = (unsigned short*)p;             p += PLANE * 2;
    unsigned short* xTl = (unsigned short*)p;             p += PLANE * 2;
    char* slotN = p;                                      p += (size_t)SLAB * NN * 2 * 2;
    unsigned short* netsh = (unsigned short*)slotN;
    unsigned short* netsl = netsh + (size_t)SLAB * NN;
    unsigned short* cwh = (unsigned short*)slotN;          // weight aliases (post-gemm_big)
    unsigned short* cwl = cwh + 512 * 512;
    unsigned short* gxh = cwl + 512 * 512;
    unsigned short* gxl = gxh + 512 * 512;
    unsigned short* gih = gxl + 512 * 512;
    unsigned short* gil = gih + 512 * 512;
    unsigned short* inth = (unsigned short*)p;            p += (size_t)SROWS * DD * 2;
    unsigned short* intl = (unsigned short*)p;            p += (size_t)SROWS * DD * 2;
    char* slotX = p;                                      p += (size_t)SROWS * DD * 4;
    unsigned short* xsh = (unsigned short*)slotX;
    unsigned short* xsl = xsh + (size_t)SROWS * DD;
    float* hplane = (float*)p;                            p += (size_t)SROWS * DD * 4;
    float* energy = (float*)p;

    // x -> transposed split planes (once)
    conv_xT<<<dim3(NN / 64, DD / 64, BB), 256, 0, stream>>>(x, xTh, xTl);

    for (int c = 0; c < 2; ++c) {
        for (int s = 0; s < 2; ++s) {
            const int nbase = s * SLAB;
            // net slab -> split planes
            conv_split<<<(SLAB * NN / 4) / 256, 256, 0, stream>>>(
                net + (size_t)c * NN * NN + (size_t)nbase * NN, netsh, netsl);
            // inter slab = net_slab @ x   (split-3 MFMA)
            gemm_big<<<dim3(DD / 128, BB, SLAB / 128), 256, 0, stream>>>(
                netsh, netsl, xTh, xTl, inth, intl);
            // weights -> split planes (into slot N, now free)
            conv_w3<<<768, 256, 0, stream>>>(
                cand_w + (size_t)c * DD * DD, gate_w + (size_t)c * DD * 2 * DD,
                cwh, cwl, gxh, gxl, gih, gil);
            // x slab -> split planes
            conv_xs<<<(SROWS * DD / 4) / 256, 256, 0, stream>>>(x, nbase, xsh, xsl);
            // fused K=1024 gate GEMM + cand GEMM + pointwise -> h (slot G)
            gemm_fused<<<dim3(4, SROWS / 128), 256, 0, stream>>>(
                xsh, xsl, inth, intl, gxh, gxl, gih, gil, cwh, cwl,
                gate_b + (size_t)c * DD, cand_b + (size_t)c * DD,
                x, nbase, hplane);
            // LN + weighted accumulate (+energy at c==1)
            pw_slab<<<SROWS, 128, 0, stream>>>(
                hplane, ln_g + (size_t)c * DD, ln_b + (size_t)c * DD,
                cmix, c, nbase, out, energy);
        }
    }

    topk_kernel<<<BB, 1024, 0, stream>>>(energy, kptr);
    mask_kernel<<<(int)ROWS, 128, 0, stream>>>(out, energy);
}